// Round 1
// baseline (1089.691 us; speedup 1.0000x reference)
//
#include <hip/hip_runtime.h>
#include <math.h>

#define BQ 4096
#define F_SUP 5
#define MAXK 64
#define ED 128
#define DM 256
#define DI 512
#define LH 512
#define NG 2048
#define PADX 200000
#define KNB 10

__device__ __forceinline__ float sigmoidf_(float x) { return 1.0f / (1.0f + expf(-x)); }

// ---------------- neighbor encoder: one block per (row, side) ----------------
__global__ __launch_bounds__(256) void neighbor_kernel(
    const int* __restrict__ query, const int* __restrict__ support,
    const int* __restrict__ q_l1, const int* __restrict__ q_deg_l,
    const int* __restrict__ q_r1, const int* __restrict__ q_deg_r,
    const int* __restrict__ s_l1, const int* __restrict__ s_deg_l,
    const int* __restrict__ s_r1, const int* __restrict__ s_deg_r,
    const float* __restrict__ emb,
    const float* __restrict__ gcn_w_w, const float* __restrict__ gcn_w_b,
    const float* __restrict__ gcn_b,
    const float* __restrict__ g1_w, const float* __restrict__ g1_b,
    const float* __restrict__ ln1_g, const float* __restrict__ ln1_b,
    const float* __restrict__ g2_w, const float* __restrict__ g2_b,
    const float* __restrict__ gate_temp,
    float* __restrict__ qv, float* __restrict__ sv)
{
  __shared__ int relS[64], entS[64];
  __shared__ __align__(16) float sE[128];
  __shared__ float simS[64];
  __shared__ int selS[16];
  __shared__ int cntS;
  __shared__ float denomS, nsS, gateS;
  __shared__ __align__(16) float rowsS[2][10][128];  // staged rel/ent rows of selected k
  __shared__ float partS[2][10][128];                // per-half partial proj
  __shared__ __align__(16) float aggS[128];

  int tid = threadIdx.x;
  int b = blockIdx.x;
  const int* conn; int deg; int self_id; float* outp;
  if (b < BQ)            { int i = b;              conn = q_l1 + i*(MAXK*2); deg = q_deg_l[i]; self_id = query[2*i];     outp = qv + i*DM; }
  else if (b < 2*BQ)     { int i = b - BQ;         conn = q_r1 + i*(MAXK*2); deg = q_deg_r[i]; self_id = query[2*i+1];   outp = qv + i*DM + ED; }
  else if (b < 2*BQ+F_SUP){int i = b - 2*BQ;       conn = s_l1 + i*(MAXK*2); deg = s_deg_l[i]; self_id = support[2*i];   outp = sv + i*DM; }
  else                   { int i = b - 2*BQ-F_SUP; conn = s_r1 + i*(MAXK*2); deg = s_deg_r[i]; self_id = support[2*i+1]; outp = sv + i*DM + ED; }

  if (tid < 128) {
    int v = conn[tid];
    if (tid & 1) entS[tid >> 1] = v; else relS[tid >> 1] = v;
    sE[tid] = emb[(long)self_id * ED + tid];
  }
  __syncthreads();
  if (tid < 64) {
    float v = sE[tid]*sE[tid] + sE[tid+64]*sE[tid+64];
    #pragma unroll
    for (int off = 1; off < 64; off <<= 1) v += __shfl_xor(v, off);
    if (tid == 0) nsS = fmaxf(sqrtf(v), 1e-12f);
  }
  __syncthreads();

  // sims: 4 lanes per k, 32 elems each
  {
    int k = tid >> 2, part = tid & 3;
    const float* er = emb + (long)entS[k] * ED + part * 32;
    const float* sr = &sE[part * 32];
    float dot = 0.f, sq = 0.f;
    #pragma unroll
    for (int j = 0; j < 32; j += 4) {
      float4 e = *(const float4*)(er + j);
      float4 s = *(const float4*)(sr + j);
      dot += e.x*s.x + e.y*s.y + e.z*s.z + e.w*s.w;
      sq  += e.x*e.x + e.y*e.y + e.z*e.z + e.w*e.w;
    }
    dot += __shfl_xor(dot, 1); dot += __shfl_xor(dot, 2);
    sq  += __shfl_xor(sq, 1);  sq  += __shfl_xor(sq, 2);
    if (part == 0) {
      float ne = fmaxf(sqrtf(sq), 1e-12f);
      float sim = dot / (nsS * ne);
      if (relS[k] == PADX) sim -= 1e9f;   // pads collapse to exactly -1e9 (fp32), as in ref
      simS[k] = sim;
    }
  }
  __syncthreads();

  // exact top-10 via rank (matches lax.top_k tie-break: value desc, index asc)
  if (tid < 64) {
    float mys = simS[tid];
    int rank = 0;
    #pragma unroll
    for (int j = 0; j < 64; ++j) {
      float s = simS[j];
      rank += ((s > mys) || (s == mys && j < tid)) ? 1 : 0;
    }
    bool sel = rank < KNB;
    bool val = sel && (relS[tid] != PADX);
    unsigned long long vm = __ballot(val ? 1 : 0);
    if (val) {
      int pos = __popcll(vm & ((1ull << tid) - 1ull));
      selS[pos] = tid;
    }
    if (tid == 0) {
      int cnt = __popcll(vm);
      cntS = cnt;
      denomS = fmaxf((float)cnt, 1.0f);
    }
  }
  __syncthreads();

  int cnt = cntS;
  // stage selected rel/ent rows (zero-fill unused slots so the proj loop is fixed-trip)
  for (int i = tid; i < 10 * 64; i += 256) {
    int kk = i >> 6, which = (i >> 5) & 1, f4 = i & 31;
    float4 v = make_float4(0.f, 0.f, 0.f, 0.f);
    if (kk < cnt) {
      int k = selS[kk];
      int id = which ? entS[k] : relS[k];
      v = *(const float4*)(emb + (long)id * ED + f4 * 4);
    }
    *(float4*)&rowsS[which][kk][f4 * 4] = v;
  }
  __syncthreads();

  // proj for selected k: j-outer so gcn_w_w streams once per block
  {
    int d = tid & 127, half = tid >> 7;
    float accp[10];
    #pragma unroll
    for (int kk = 0; kk < 10; ++kk) accp[kk] = 0.f;
    const float* wrow = gcn_w_w + d * DM + half * ED;
    #pragma unroll 4
    for (int j = 0; j < 128; ++j) {
      float w = wrow[j];
      #pragma unroll
      for (int kk = 0; kk < 10; ++kk) accp[kk] += w * rowsS[half][kk][j];
    }
    #pragma unroll
    for (int kk = 0; kk < 10; ++kk) partS[half][kk][d] = accp[kk];
  }
  __syncthreads();

  if (tid < 128) {
    int d = tid;
    float bsum = gcn_w_b[d] + gcn_b[d];
    float agg = 0.f;
    #pragma unroll
    for (int kk = 0; kk < 10; ++kk) {
      if (kk < cnt) {
        float z = partS[0][kk][d] + partS[1][kk][d] + bsum;
        z = (z >= 0.f) ? z : 0.01f * z;   // leaky_relu
        agg += z;
      }
    }
    agg /= denomS;
    aggS[d] = agg;
  }
  __syncthreads();

  // gate MLP on wave 0: 128->64, LN, relu, ->1
  if (tid < 64) {
    int e = tid;
    const float* g1r = g1_w + e * ED;
    float y = g1_b[e];
    #pragma unroll 4
    for (int j = 0; j < 128; ++j) y += aggS[j] * g1r[j];
    float s = y;
    #pragma unroll
    for (int off = 1; off < 64; off <<= 1) s += __shfl_xor(s, off);
    float mean = s * (1.0f / 64.0f);
    float dv = y - mean;
    float s2 = dv * dv;
    #pragma unroll
    for (int off = 1; off < 64; off <<= 1) s2 += __shfl_xor(s2, off);
    float var = s2 * (1.0f / 64.0f);
    float hv = dv / sqrtf(var + 1e-5f) * ln1_g[e] + ln1_b[e];
    hv = fmaxf(hv, 0.f);
    float lp = hv * g2_w[e];
    #pragma unroll
    for (int off = 1; off < 64; off <<= 1) lp += __shfl_xor(lp, off);
    if (e == 0) {
      float logit = lp + g2_b[0];
      float temp = fminf(fmaxf(gate_temp[0], 0.1f), 5.0f);
      float gate = sigmoidf_(logit / temp);
      if (deg <= 0) gate = 0.f;
      gateS = gate;
    }
  }
  __syncthreads();

  if (tid < 128) outp[tid] = tanhf(sE[tid] + gateS * aggS[tid]);
}

// ---------------- support encoder for the 5 support rows ----------------
__global__ __launch_bounds__(256) void support_enc_kernel(
    const float* __restrict__ x, const float* __restrict__ p1, const float* __restrict__ b1,
    const float* __restrict__ p2, const float* __restrict__ b2,
    const float* __restrict__ lng, const float* __restrict__ lnb,
    float* __restrict__ out)
{
  __shared__ float xS[DM];
  __shared__ float h1S[DI];
  __shared__ float red[4];
  int r = blockIdx.x, tid = threadIdx.x;
  xS[tid] = x[r * DM + tid];
  __syncthreads();
  float a0 = b1[tid], a1 = b1[tid + 256];
  const float* w0 = p1 + tid * DM;
  const float* w1 = p1 + (tid + 256) * DM;
  #pragma unroll 4
  for (int j = 0; j < DM; ++j) { float xv = xS[j]; a0 += xv * w0[j]; a1 += xv * w1[j]; }
  h1S[tid] = fmaxf(a0, 0.f); h1S[tid + 256] = fmaxf(a1, 0.f);
  __syncthreads();
  float h2 = b2[tid] + xS[tid];
  const float* w2 = p2 + tid * DI;
  #pragma unroll 4
  for (int j = 0; j < DI; ++j) h2 += h1S[j] * w2[j];
  float s = h2;
  #pragma unroll
  for (int off = 1; off < 64; off <<= 1) s += __shfl_xor(s, off);
  if ((tid & 63) == 0) red[tid >> 6] = s;
  __syncthreads();
  float mean = (red[0] + red[1] + red[2] + red[3]) * (1.0f / 256.0f);
  __syncthreads();
  float dv = h2 - mean;
  float s2 = dv * dv;
  #pragma unroll
  for (int off = 1; off < 64; off <<= 1) s2 += __shfl_xor(s2, off);
  if ((tid & 63) == 0) red[tid >> 6] = s2;
  __syncthreads();
  float var = (red[0] + red[1] + red[2] + red[3]) * (1.0f / 256.0f);
  out[r * DM + tid] = dv / sqrtf(var + 1e-5f) * lng[tid] + lnb[tid];
}

// ---------------- support_g = mean(senc); s_corr = support_g @ w_hh[:,256:]^T ----------------
__global__ __launch_bounds__(256) void support_g_kernel(
    const float* __restrict__ senc, const float* __restrict__ w_hh,
    float* __restrict__ sg, float* __restrict__ s_corr)
{
  __shared__ float sgS[DM];
  int tid = threadIdx.x;
  float v = 0.f;
  #pragma unroll
  for (int r = 0; r < F_SUP; ++r) v += senc[r * DM + tid];
  v = v / (float)F_SUP;
  sg[tid] = v; sgS[tid] = v;
  __syncthreads();
  for (int it = 0; it < 8; ++it) {
    int n = tid + it * 256;
    const float* wr = w_hh + (long)n * LH + DM;
    float a = 0.f;
    #pragma unroll 4
    for (int j = 0; j < DM; ++j) a += sgS[j] * wr[j];
    s_corr[n] = a;
  }
}

// ---------------- generic fp32 GEMM: C[M,N] = A[M,K] @ W[N,K]^T (+biases, +addfull, relu) ----------------
__global__ __launch_bounds__(256) void gemm_atw_kernel(
    const float* __restrict__ A, int lda,
    const float* __restrict__ W, int ldw,
    float* __restrict__ C, int M, int N, int K,
    const float* __restrict__ bias0, const float* __restrict__ bias1,
    const float* __restrict__ addfull, int relu)
{
  __shared__ __align__(16) float As[32][132];
  __shared__ __align__(16) float Ws[32][132];
  int tid = threadIdx.x;
  int nb = N >> 7;
  int bn = blockIdx.x % nb;
  int bm = blockIdx.x / nb;
  int tx = tid & 15, ty = tid >> 4;
  int m0 = bm * 128 + ty * 8;
  int n0 = bn * 128 + tx * 8;
  float acc[8][8];
  #pragma unroll
  for (int i = 0; i < 8; ++i)
    #pragma unroll
    for (int j = 0; j < 8; ++j) acc[i][j] = 0.f;

  for (int k0 = 0; k0 < K; k0 += 32) {
    #pragma unroll
    for (int it = 0; it < 4; ++it) {
      int i = tid + it * 256;
      int r = i >> 3, c4 = i & 7;
      float4 va = *(const float4*)(A + (long)(bm * 128 + r) * lda + k0 + c4 * 4);
      As[c4*4+0][r] = va.x; As[c4*4+1][r] = va.y; As[c4*4+2][r] = va.z; As[c4*4+3][r] = va.w;
      float4 vw = *(const float4*)(W + (long)(bn * 128 + r) * ldw + k0 + c4 * 4);
      Ws[c4*4+0][r] = vw.x; Ws[c4*4+1][r] = vw.y; Ws[c4*4+2][r] = vw.z; Ws[c4*4+3][r] = vw.w;
    }
    __syncthreads();
    #pragma unroll
    for (int k = 0; k < 32; ++k) {
      float a[8], w[8];
      #pragma unroll
      for (int i = 0; i < 8; ++i) a[i] = As[k][ty * 8 + i];
      #pragma unroll
      for (int j = 0; j < 8; ++j) w[j] = Ws[k][tx * 8 + j];
      #pragma unroll
      for (int i = 0; i < 8; ++i)
        #pragma unroll
        for (int j = 0; j < 8; ++j) acc[i][j] += a[i] * w[j];
    }
    __syncthreads();
  }
  #pragma unroll
  for (int i = 0; i < 8; ++i) {
    int m = m0 + i;
    #pragma unroll
    for (int j = 0; j < 8; ++j) {
      int n = n0 + j;
      float v = acc[i][j];
      if (bias0) v += bias0[n];
      if (bias1) v += bias1[n];
      if (addfull) v += addfull[(long)m * N + n];
      if (relu) v = fmaxf(v, 0.f);
      C[(long)m * N + n] = v;
    }
  }
}

// ---------------- residual layernorm: out = LN(h2 + x) ----------------
__global__ __launch_bounds__(256) void ln_residual_kernel(
    const float* __restrict__ h2buf, const float* __restrict__ xbuf,
    const float* __restrict__ lng, const float* __restrict__ lnb,
    float* __restrict__ out)
{
  __shared__ float red[4];
  int r = blockIdx.x, tid = threadIdx.x;
  float v = h2buf[(long)r * DM + tid] + xbuf[(long)r * DM + tid];
  float s = v;
  #pragma unroll
  for (int off = 1; off < 64; off <<= 1) s += __shfl_xor(s, off);
  if ((tid & 63) == 0) red[tid >> 6] = s;
  __syncthreads();
  float mean = (red[0] + red[1] + red[2] + red[3]) * (1.0f / 256.0f);
  __syncthreads();
  float dv = v - mean;
  float s2 = dv * dv;
  #pragma unroll
  for (int off = 1; off < 64; off <<= 1) s2 += __shfl_xor(s2, off);
  if ((tid & 63) == 0) red[tid >> 6] = s2;
  __syncthreads();
  float var = (red[0] + red[1] + red[2] + red[3]) * (1.0f / 256.0f);
  out[(long)r * DM + tid] = dv / sqrtf(var + 1e-5f) * lng[tid] + lnb[tid];
}

// ---------------- LSTM elementwise ----------------
__global__ __launch_bounds__(256) void lstm_elem_kernel(
    const float* __restrict__ gates, const float* __restrict__ qe,
    float* __restrict__ c, float* __restrict__ h, int first)
{
  int gid = blockIdx.x * 256 + threadIdx.x;   // over BQ*LH
  int m = gid >> 9, n = gid & 511;
  const float* gr = gates + (long)m * NG;
  float gi = gr[n], gf = gr[n + 512], gg = gr[n + 1024], go = gr[n + 1536];
  float cp = first ? 0.f : c[gid];
  float cn = sigmoidf_(gf) * cp + sigmoidf_(gi) * tanhf(gg);
  c[gid] = cn;
  if (n < 256) h[(long)m * DM + n] = qe[(long)m * DM + n] + sigmoidf_(go) * tanhf(cn);
}

// ---------------- final dot with support_g ----------------
__global__ __launch_bounds__(256) void final_dot_kernel(
    const float* __restrict__ h, const float* __restrict__ sg, float* __restrict__ out)
{
  __shared__ float red[4];
  int m = blockIdx.x, tid = threadIdx.x;
  float v = h[(long)m * DM + tid] * sg[tid];
  #pragma unroll
  for (int off = 1; off < 64; off <<= 1) v += __shfl_xor(v, off);
  if ((tid & 63) == 0) red[tid >> 6] = v;
  __syncthreads();
  if (tid == 0) out[m] = red[0] + red[1] + red[2] + red[3];
}

extern "C" void kernel_launch(void* const* d_in, const int* in_sizes, int n_in,
                              void* d_out, int out_size, void* d_ws, size_t ws_size,
                              hipStream_t stream)
{
  const int*   query    = (const int*)  d_in[0];
  const int*   support  = (const int*)  d_in[1];
  const int*   q_l1     = (const int*)  d_in[2];
  const int*   q_deg_l  = (const int*)  d_in[3];
  const int*   q_r1     = (const int*)  d_in[4];
  const int*   q_deg_r  = (const int*)  d_in[5];
  const int*   s_l1     = (const int*)  d_in[6];
  const int*   s_deg_l  = (const int*)  d_in[7];
  const int*   s_r1     = (const int*)  d_in[8];
  const int*   s_deg_r  = (const int*)  d_in[9];
  const float* symbol_emb = (const float*)d_in[10];
  const float* gcn_w_w  = (const float*)d_in[11];
  const float* gcn_w_b  = (const float*)d_in[12];
  const float* gcn_b    = (const float*)d_in[13];
  const float* g1_w     = (const float*)d_in[14];
  const float* g1_b     = (const float*)d_in[15];
  const float* ln1_g    = (const float*)d_in[16];
  const float* ln1_b    = (const float*)d_in[17];
  const float* g2_w     = (const float*)d_in[18];
  const float* g2_b     = (const float*)d_in[19];
  const float* gate_temp= (const float*)d_in[20];
  const float* se_p1_w  = (const float*)d_in[21];
  const float* se_p1_b  = (const float*)d_in[22];
  const float* se_p2_w  = (const float*)d_in[23];
  const float* se_p2_b  = (const float*)d_in[24];
  const float* se_ln_g  = (const float*)d_in[25];
  const float* se_ln_b  = (const float*)d_in[26];
  const float* w_ih     = (const float*)d_in[27];
  const float* w_hh     = (const float*)d_in[28];
  const float* b_ih     = (const float*)d_in[29];
  const float* b_hh     = (const float*)d_in[30];

  float* ws = (float*)d_ws;
  size_t off = 0;
  float* qv     = ws + off; off += (size_t)BQ * DM;   // 4096x256
  float* sv     = ws + off; off += (size_t)F_SUP * DM;
  float* senc   = ws + off; off += (size_t)F_SUP * DM;
  float* sg     = ws + off; off += DM;
  float* s_corr = ws + off; off += NG;
  float* qe     = ws + off; off += (size_t)BQ * DM;
  float* hbuf   = ws + off; off += (size_t)BQ * DM;
  float* cbuf   = ws + off; off += (size_t)BQ * LH;
  float* gq     = ws + off; off += (size_t)BQ * NG;   // 4096x2048
  float* gates  = ws + off; off += (size_t)BQ * NG;
  // aliases (lifetimes don't overlap):
  float* H1 = gq;     // 4096x512, dead before gq GEMM writes
  float* H2 = gates;  // 4096x256, dead before step-2 GEMM writes gates

  // 1. neighbor encoders -> query_vec, support_vec
  neighbor_kernel<<<2 * BQ + 2 * F_SUP, 256, 0, stream>>>(
      query, support, q_l1, q_deg_l, q_r1, q_deg_r, s_l1, s_deg_l, s_r1, s_deg_r,
      symbol_emb, gcn_w_w, gcn_w_b, gcn_b, g1_w, g1_b, ln1_g, ln1_b, g2_w, g2_b,
      gate_temp, qv, sv);

  // 2. support rows encoded, mean -> sg, s_corr
  support_enc_kernel<<<F_SUP, 256, 0, stream>>>(sv, se_p1_w, se_p1_b, se_p2_w, se_p2_b,
                                                se_ln_g, se_ln_b, senc);
  support_g_kernel<<<1, 256, 0, stream>>>(senc, w_hh, sg, s_corr);

  // 3. query encoder: H1 = relu(qv@p1^T+b1); H2 = H1@p2^T+b2; qe = LN(H2+qv)
  gemm_atw_kernel<<<(BQ / 128) * (DI / 128), 256, 0, stream>>>(
      qv, DM, se_p1_w, DM, H1, BQ, DI, DM, se_p1_b, nullptr, nullptr, 1);
  gemm_atw_kernel<<<(BQ / 128) * (DM / 128), 256, 0, stream>>>(
      H1, DI, se_p2_w, DI, H2, BQ, DM, DI, se_p2_b, nullptr, nullptr, 0);
  ln_residual_kernel<<<BQ, 256, 0, stream>>>(H2, qv, se_ln_g, se_ln_b, qe);

  // 4. gq = qe@w_ih^T + b_ih + b_hh  (constant over steps)
  gemm_atw_kernel<<<(BQ / 128) * (NG / 128), 256, 0, stream>>>(
      qe, DM, w_ih, DM, gq, BQ, NG, DM, b_ih, b_hh, nullptr, 0);

  // 5. LSTM step 1: gates == gq (h_r = 0)
  lstm_elem_kernel<<<(BQ * LH) / 256, 256, 0, stream>>>(gq, qe, cbuf, hbuf, 1);

  // steps 2..4: gates = gq + h@w_hh[:,:256]^T + s_corr
  for (int s = 2; s <= 4; ++s) {
    gemm_atw_kernel<<<(BQ / 128) * (NG / 128), 256, 0, stream>>>(
        hbuf, DM, w_hh, LH, gates, BQ, NG, DM, s_corr, nullptr, gq, 0);
    lstm_elem_kernel<<<(BQ * LH) / 256, 256, 0, stream>>>(gates, qe, cbuf, hbuf, 0);
  }

  // 6. out[m] = dot(h[m], support_g)
  final_dot_kernel<<<BQ, 256, 0, stream>>>(hbuf, sg, (float*)d_out);
}

// Round 2
// 775.221 us; speedup vs baseline: 1.4057x; 1.4057x over previous
//
#include <hip/hip_runtime.h>
#include <math.h>

#define BQ 4096
#define F_SUP 5
#define MAXK 64
#define ED 128
#define DM 256
#define DI 512
#define LH 512
#define NG 2048
#define PADX 200000
#define KNB 10

typedef unsigned short u16;
typedef __attribute__((ext_vector_type(8))) short short8;
typedef __attribute__((ext_vector_type(4))) float floatx4;

__device__ __forceinline__ float sigf(float x) { return 1.0f / (1.0f + __expf(-x)); }
__device__ __forceinline__ float tanh_fast(float x) {
  float a = fabsf(x);
  float e = __expf(-2.0f * a);
  float t = (1.0f - e) / (1.0f + e);
  return copysignf(t, x);
}
__device__ __forceinline__ u16 f2bf(float f) {
  unsigned u = __float_as_uint(f);
  unsigned r = (u + 0x7FFFu + ((u >> 16) & 1u)) >> 16;
  return (u16)r;
}
__device__ __forceinline__ void gl2lds16(const void* g, void* l) {
  __builtin_amdgcn_global_load_lds(
      (const __attribute__((address_space(1))) void*)g,
      (__attribute__((address_space(3))) void*)l, 16, 0, 0);
}

// ============ phase A: gather + sims + top-k -> packed bf16 R rows ============
__global__ __launch_bounds__(256) void nbr_topk_kernel(
    const int* __restrict__ query, const int* __restrict__ support,
    const int* __restrict__ q_l1, const int* __restrict__ q_r1,
    const int* __restrict__ s_l1, const int* __restrict__ s_r1,
    const float* __restrict__ emb,
    u16* __restrict__ Rbf, int* __restrict__ meta)
{
  __shared__ int relS[64], entS[64];
  __shared__ __align__(16) float sE[128];
  __shared__ float simS[64];
  __shared__ int selS[16];
  __shared__ int cntS;
  __shared__ float nsS;

  int tid = threadIdx.x;
  int b = blockIdx.x;
  const int* conn; int self_id;
  if (b < BQ)              { int i = b;              conn = q_l1 + i*(MAXK*2); self_id = query[2*i];   }
  else if (b < 2*BQ)       { int i = b - BQ;         conn = q_r1 + i*(MAXK*2); self_id = query[2*i+1]; }
  else if (b < 2*BQ+F_SUP) { int i = b - 2*BQ;       conn = s_l1 + i*(MAXK*2); self_id = support[2*i]; }
  else                     { int i = b - 2*BQ-F_SUP; conn = s_r1 + i*(MAXK*2); self_id = support[2*i+1]; }

  if (tid < 128) {
    int v = conn[tid];
    if (tid & 1) entS[tid >> 1] = v; else relS[tid >> 1] = v;
    sE[tid] = emb[(long)self_id * ED + tid];
  }
  __syncthreads();
  if (tid < 64) {
    float v = sE[tid]*sE[tid] + sE[tid+64]*sE[tid+64];
    #pragma unroll
    for (int off = 1; off < 64; off <<= 1) v += __shfl_xor(v, off);
    if (tid == 0) nsS = fmaxf(sqrtf(v), 1e-12f);
  }
  __syncthreads();

  {
    int k = tid >> 2, part = tid & 3;
    const float* er = emb + (long)entS[k] * ED + part * 32;
    const float* sr = &sE[part * 32];
    float dot = 0.f, sq = 0.f;
    #pragma unroll
    for (int j = 0; j < 32; j += 4) {
      float4 e = *(const float4*)(er + j);
      float4 s = *(const float4*)(sr + j);
      dot += e.x*s.x + e.y*s.y + e.z*s.z + e.w*s.w;
      sq  += e.x*e.x + e.y*e.y + e.z*e.z + e.w*e.w;
    }
    dot += __shfl_xor(dot, 1); dot += __shfl_xor(dot, 2);
    sq  += __shfl_xor(sq, 1);  sq  += __shfl_xor(sq, 2);
    if (part == 0) {
      float ne = fmaxf(sqrtf(sq), 1e-12f);
      float sim = dot / (nsS * ne);
      if (relS[k] == PADX) sim -= 1e9f;
      simS[k] = sim;
    }
  }
  __syncthreads();

  if (tid < 64) {
    float mys = simS[tid];
    int rank = 0;
    #pragma unroll
    for (int j = 0; j < 64; ++j) {
      float s = simS[j];
      rank += ((s > mys) || (s == mys && j < tid)) ? 1 : 0;
    }
    bool val = (rank < KNB) && (relS[tid] != PADX);
    unsigned long long vm = __ballot(val ? 1 : 0);
    if (val) {
      int pos = __popcll(vm & ((1ull << tid) - 1ull));
      selS[pos] = tid;
    }
    if (tid == 0) { cntS = __popcll(vm); meta[b] = __popcll(vm); }
  }
  __syncthreads();

  int cnt = cntS;
  long base = (long)b * 10;
  for (int i = tid; i < cnt * 256; i += 256) {
    int kk = i >> 8, col = i & 255;
    int k = selS[kk];
    int id = (col < 128) ? relS[k] : entS[k];
    float v = emb[(long)id * ED + (col & 127)];
    Rbf[(base + kk) * 256 + col] = f2bf(v);
  }
}

// ============ phase C: leaky/sum + gate MLP + tanh output ============
__global__ __launch_bounds__(128) void nbr_post_kernel(
    const int* __restrict__ query, const int* __restrict__ support,
    const int* __restrict__ q_deg_l, const int* __restrict__ q_deg_r,
    const int* __restrict__ s_deg_l, const int* __restrict__ s_deg_r,
    const float* __restrict__ emb,
    const float* __restrict__ proj, const int* __restrict__ meta,
    const float* __restrict__ gcn_w_b, const float* __restrict__ gcn_b,
    const float* __restrict__ g1_w, const float* __restrict__ g1_b,
    const float* __restrict__ ln1_g, const float* __restrict__ ln1_b,
    const float* __restrict__ g2_w, const float* __restrict__ g2_b,
    const float* __restrict__ gate_temp,
    float* __restrict__ qv, u16* __restrict__ qv_bf, float* __restrict__ sv)
{
  __shared__ __align__(16) float aggS[128];
  __shared__ float sEs[128];
  __shared__ float gateS;
  int tid = threadIdx.x, b = blockIdx.x;
  int deg, self_id; float* outp; u16* outpb;
  if (b < BQ)              { int i = b;              deg = q_deg_l[i]; self_id = query[2*i];     outp = qv + (long)i*DM;      outpb = qv_bf + (long)i*DM; }
  else if (b < 2*BQ)       { int i = b - BQ;         deg = q_deg_r[i]; self_id = query[2*i+1];   outp = qv + (long)i*DM + ED; outpb = qv_bf + (long)i*DM + ED; }
  else if (b < 2*BQ+F_SUP) { int i = b - 2*BQ;       deg = s_deg_l[i]; self_id = support[2*i];   outp = sv + (long)i*DM;      outpb = nullptr; }
  else                     { int i = b - 2*BQ-F_SUP; deg = s_deg_r[i]; self_id = support[2*i+1]; outp = sv + (long)i*DM + ED; outpb = nullptr; }

  int cnt = meta[b];
  float denom = fmaxf((float)cnt, 1.0f);
  float bsum = gcn_w_b[tid] + gcn_b[tid];
  float agg = 0.f;
  long pbase = (long)b * 10;
  for (int kk = 0; kk < cnt; ++kk) {
    float z = proj[(pbase + kk) * 128 + tid] + bsum;
    z = (z >= 0.f) ? z : 0.01f * z;
    agg += z;
  }
  agg /= denom;
  aggS[tid] = agg;
  sEs[tid] = emb[(long)self_id * ED + tid];
  __syncthreads();

  if (tid < 64) {
    int e = tid;
    const float4* g1r = (const float4*)(g1_w + e * ED);
    float y = g1_b[e];
    #pragma unroll 8
    for (int j = 0; j < 32; ++j) {
      float4 w = g1r[j];
      float4 a = *(const float4*)&aggS[j * 4];
      y += w.x*a.x + w.y*a.y + w.z*a.z + w.w*a.w;
    }
    float s = y;
    #pragma unroll
    for (int off = 1; off < 64; off <<= 1) s += __shfl_xor(s, off);
    float mean = s * (1.0f / 64.0f);
    float dv = y - mean;
    float s2 = dv * dv;
    #pragma unroll
    for (int off = 1; off < 64; off <<= 1) s2 += __shfl_xor(s2, off);
    float var = s2 * (1.0f / 64.0f);
    float hv = dv / sqrtf(var + 1e-5f) * ln1_g[e] + ln1_b[e];
    hv = fmaxf(hv, 0.f);
    float lp = hv * g2_w[e];
    #pragma unroll
    for (int off = 1; off < 64; off <<= 1) lp += __shfl_xor(lp, off);
    if (e == 0) {
      float logit = lp + g2_b[0];
      float temp = fminf(fmaxf(gate_temp[0], 0.1f), 5.0f);
      float gate = 1.0f / (1.0f + expf(-logit / temp));
      if (deg <= 0) gate = 0.f;
      gateS = gate;
    }
  }
  __syncthreads();
  float o = tanhf(sEs[tid] + gateS * aggS[tid]);
  outp[tid] = o;
  if (outpb) outpb[tid] = f2bf(o);
}

// ============ MFMA bf16 GEMM: C[M,N] = A[M,K] @ W[N,K]^T, optional LSTM epilogue ============
__global__ __launch_bounds__(256) void mfma_gemm(
    const u16* __restrict__ A, int lda,
    const u16* __restrict__ W, int ldw,
    int N, int K,
    float* __restrict__ Cout, u16* __restrict__ Cbf,
    const float* __restrict__ bias0, const float* __restrict__ addfull,
    int relu, int lstm_mode,
    float* __restrict__ cstate, const float* __restrict__ qe,
    float* __restrict__ hout, u16* __restrict__ hbf)
{
  __shared__ u16 As[128 * 32];
  __shared__ u16 Bs[128 * 32];
  int tid = threadIdx.x;
  int nb = N >> 7;
  int bn = blockIdx.x % nb, bm = blockIdx.x / nb;
  int lane = tid & 63, wave = tid >> 6;
  int wm = (wave & 1) * 64, wn = (wave >> 1) * 64;
  int col = lane & 15, quad = lane >> 4;

  floatx4 acc[4][4];
  #pragma unroll
  for (int i = 0; i < 4; ++i)
    #pragma unroll
    for (int j = 0; j < 4; ++j) {
      floatx4 z = {0.f, 0.f, 0.f, 0.f};
      acc[i][j] = z;
    }

  for (int k0 = 0; k0 < K; k0 += 32) {
    #pragma unroll
    for (int t = 0; t < 2; ++t) {
      int c = t * 256 + tid;
      int r = c >> 2, o = c & 3;
      int og = o ^ (r & 3);
      gl2lds16(A + (long)(bm * 128 + r) * lda + k0 + og * 8, &As[(size_t)c * 8]);
      gl2lds16(W + (long)(bn * 128 + r) * ldw + k0 + og * 8, &Bs[(size_t)c * 8]);
    }
    __syncthreads();
    short8 af[4], bfr[4];
    #pragma unroll
    for (int i = 0; i < 4; ++i) {
      int ra = wm + i * 16 + col;
      af[i] = *(const short8*)&As[(size_t)(ra * 4 + (quad ^ (ra & 3))) * 8];
      int rb = wn + i * 16 + col;
      bfr[i] = *(const short8*)&Bs[(size_t)(rb * 4 + (quad ^ (rb & 3))) * 8];
    }
    #pragma unroll
    for (int i = 0; i < 4; ++i)
      #pragma unroll
      for (int j = 0; j < 4; ++j)
        acc[i][j] = __builtin_amdgcn_mfma_f32_16x16x32_bf16(af[i], bfr[j], acc[i][j], 0, 0, 0);
    __syncthreads();
  }

  int gm0 = bm * 128 + wm + quad * 4;
  int gn0 = bn * 128 + wn + col;
  #pragma unroll
  for (int i = 0; i < 4; ++i) {
    #pragma unroll
    for (int j = 0; j < 4; ++j) {
      int n = gn0 + j * 16;
      #pragma unroll
      for (int r = 0; r < 4; ++r) {
        int m = gm0 + i * 16 + r;
        float v = acc[i][j][r];
        if (bias0) v += bias0[n];
        if (addfull) v += addfull[(long)m * N + n];
        if (!lstm_mode) {
          if (relu) v = fmaxf(v, 0.f);
          if (Cout) Cout[(long)m * N + n] = v;
          if (Cbf)  Cbf[(long)m * N + n] = f2bf(v);
        } else {
          int g = n & 3;
          float t = (g == 2) ? tanh_fast(v) : sigf(v);
          float t1 = __shfl_xor(t, 1);
          float t2 = __shfl_xor(t, 2);
          float t3 = __shfl_xor(t, 3);
          if (g == 0) {
            int n4 = n >> 2;
            long ci = (long)m * LH + n4;
            float cn = t1 * cstate[ci] + t * t2;
            cstate[ci] = cn;
            if (n4 < DM) {
              float hv = qe[(long)m * DM + n4] + t3 * tanh_fast(cn);
              if (hout) hout[(long)m * DM + n4] = hv;
              hbf[(long)m * DM + n4] = f2bf(hv);
            }
          }
        }
      }
    }
  }
}

// ============ weight casts + gate-permuted layouts ============
__global__ void prep_cast(
    const float* __restrict__ p1, const float* __restrict__ p2,
    const float* __restrict__ gcnw, const float* __restrict__ wih,
    const float* __restrict__ whh, const float* __restrict__ bih,
    const float* __restrict__ bhh,
    u16* __restrict__ p1b, u16* __restrict__ p2b, u16* __restrict__ gcnb,
    u16* __restrict__ wihb, u16* __restrict__ whhb, float* __restrict__ bihh)
{
  int gid = blockIdx.x * 256 + threadIdx.x;
  if (gid < 131072) { p1b[gid] = f2bf(p1[gid]); }
  else if (gid < 262144) { int i = gid - 131072; p2b[i] = f2bf(p2[i]); }
  else if (gid < 294912) { int i = gid - 262144; gcnb[i] = f2bf(gcnw[i]); }
  else if (gid < 819200) {
    int i = gid - 294912; int npp = i >> 8, k = i & 255;
    int n = (npp & 3) * LH + (npp >> 2);
    wihb[i] = f2bf(wih[(long)n * DM + k]);
  } else if (gid < 1343488) {
    int i = gid - 819200; int npp = i >> 8, k = i & 255;
    int n = (npp & 3) * LH + (npp >> 2);
    whhb[i] = f2bf(whh[(long)n * LH + k]);   // left half cols 0..255
  } else if (gid < 1345536) {
    int i = gid - 1343488;
    int n = ((i & 3) * LH) + (i >> 2);
    bihh[i] = bih[n] + bhh[n];
  }
}

// ============ support encoder (5 rows, fp32 exact) ============
__global__ __launch_bounds__(256) void support_enc_kernel(
    const float* __restrict__ x, const float* __restrict__ p1, const float* __restrict__ b1,
    const float* __restrict__ p2, const float* __restrict__ b2,
    const float* __restrict__ lng, const float* __restrict__ lnb,
    float* __restrict__ out)
{
  __shared__ float xS[DM];
  __shared__ float h1S[DI];
  __shared__ float red[4];
  int r = blockIdx.x, tid = threadIdx.x;
  xS[tid] = x[r * DM + tid];
  __syncthreads();
  float a0 = b1[tid], a1 = b1[tid + 256];
  const float* w0 = p1 + tid * DM;
  const float* w1 = p1 + (tid + 256) * DM;
  #pragma unroll 4
  for (int j = 0; j < DM; ++j) { float xv = xS[j]; a0 += xv * w0[j]; a1 += xv * w1[j]; }
  h1S[tid] = fmaxf(a0, 0.f); h1S[tid + 256] = fmaxf(a1, 0.f);
  __syncthreads();
  float h2 = b2[tid] + xS[tid];
  const float* w2 = p2 + tid * DI;
  #pragma unroll 4
  for (int j = 0; j < DI; ++j) h2 += h1S[j] * w2[j];
  float s = h2;
  #pragma unroll
  for (int off = 1; off < 64; off <<= 1) s += __shfl_xor(s, off);
  if ((tid & 63) == 0) red[tid >> 6] = s;
  __syncthreads();
  float mean = (red[0] + red[1] + red[2] + red[3]) * (1.0f / 256.0f);
  __syncthreads();
  float dv = h2 - mean;
  float s2 = dv * dv;
  #pragma unroll
  for (int off = 1; off < 64; off <<= 1) s2 += __shfl_xor(s2, off);
  if ((tid & 63) == 0) red[tid >> 6] = s2;
  __syncthreads();
  float var = (red[0] + red[1] + red[2] + red[3]) * (1.0f / 256.0f);
  out[r * DM + tid] = dv / sqrtf(var + 1e-5f) * lng[tid] + lnb[tid];
}

// ============ support_g + permuted s_corr ============
__global__ __launch_bounds__(256) void support_g_kernel(
    const float* __restrict__ senc, const float* __restrict__ w_hh,
    float* __restrict__ sg, float* __restrict__ s_corr_perm)
{
  __shared__ float sgS[DM];
  int tid = threadIdx.x;
  float v = 0.f;
  #pragma unroll
  for (int r = 0; r < F_SUP; ++r) v += senc[r * DM + tid];
  v = v / (float)F_SUP;
  sg[tid] = v; sgS[tid] = v;
  __syncthreads();
  for (int it = 0; it < 8; ++it) {
    int n = tid + it * 256;
    const float* wr = w_hh + (long)n * LH + DM;
    float a = 0.f;
    #pragma unroll 4
    for (int j = 0; j < DM; ++j) a += sgS[j] * wr[j];
    s_corr_perm[((n & 511) << 2) | (n >> 9)] = a;
  }
}

// ============ residual layernorm -> qe (fp32 + bf16) ============
__global__ __launch_bounds__(256) void ln_residual_kernel(
    const float* __restrict__ h2buf, const float* __restrict__ xbuf,
    const float* __restrict__ lng, const float* __restrict__ lnb,
    float* __restrict__ out, u16* __restrict__ outb)
{
  __shared__ float red[4];
  int r = blockIdx.x, tid = threadIdx.x;
  float v = h2buf[(long)r * DM + tid] + xbuf[(long)r * DM + tid];
  float s = v;
  #pragma unroll
  for (int off = 1; off < 64; off <<= 1) s += __shfl_xor(s, off);
  if ((tid & 63) == 0) red[tid >> 6] = s;
  __syncthreads();
  float mean = (red[0] + red[1] + red[2] + red[3]) * (1.0f / 256.0f);
  __syncthreads();
  float dv = v - mean;
  float s2 = dv * dv;
  #pragma unroll
  for (int off = 1; off < 64; off <<= 1) s2 += __shfl_xor(s2, off);
  if ((tid & 63) == 0) red[tid >> 6] = s2;
  __syncthreads();
  float var = (red[0] + red[1] + red[2] + red[3]) * (1.0f / 256.0f);
  float o = dv / sqrtf(var + 1e-5f) * lng[tid] + lnb[tid];
  out[(long)r * DM + tid] = o;
  outb[(long)r * DM + tid] = f2bf(o);
}

// ============ LSTM step 1 (h0=0): gates == gq_perm ============
__global__ __launch_bounds__(256) void lstm_first_kernel(
    const float* __restrict__ gq_perm, const float* __restrict__ qe,
    float* __restrict__ cstate, u16* __restrict__ hbf)
{
  int gid = blockIdx.x * 256 + threadIdx.x;  // over BQ*LH
  int m = gid >> 9, n4 = gid & 511;
  float4 gv = *(const float4*)(gq_perm + (long)m * NG + n4 * 4);  // i,f,g,o
  float cn = sigf(gv.x) * tanh_fast(gv.z);                        // sig(f)*0 + sig(i)*tanh(g)
  cstate[gid] = cn;
  if (n4 < DM) {
    float hv = qe[(long)m * DM + n4] + sigf(gv.w) * tanh_fast(cn);
    hbf[(long)m * DM + n4] = f2bf(hv);
  }
}

// ============ final dot ============
__global__ __launch_bounds__(256) void final_dot_kernel(
    const float* __restrict__ h, const float* __restrict__ sg, float* __restrict__ out)
{
  __shared__ float red[4];
  int m = blockIdx.x, tid = threadIdx.x;
  float v = h[(long)m * DM + tid] * sg[tid];
  #pragma unroll
  for (int off = 1; off < 64; off <<= 1) v += __shfl_xor(v, off);
  if ((tid & 63) == 0) red[tid >> 6] = v;
  __syncthreads();
  if (tid == 0) out[m] = red[0] + red[1] + red[2] + red[3];
}

extern "C" void kernel_launch(void* const* d_in, const int* in_sizes, int n_in,
                              void* d_out, int out_size, void* d_ws, size_t ws_size,
                              hipStream_t stream)
{
  const int*   query    = (const int*)  d_in[0];
  const int*   support  = (const int*)  d_in[1];
  const int*   q_l1     = (const int*)  d_in[2];
  const int*   q_deg_l  = (const int*)  d_in[3];
  const int*   q_r1     = (const int*)  d_in[4];
  const int*   q_deg_r  = (const int*)  d_in[5];
  const int*   s_l1     = (const int*)  d_in[6];
  const int*   s_deg_l  = (const int*)  d_in[7];
  const int*   s_r1     = (const int*)  d_in[8];
  const int*   s_deg_r  = (const int*)  d_in[9];
  const float* symbol_emb = (const float*)d_in[10];
  const float* gcn_w_w  = (const float*)d_in[11];
  const float* gcn_w_b  = (const float*)d_in[12];
  const float* gcn_b    = (const float*)d_in[13];
  const float* g1_w     = (const float*)d_in[14];
  const float* g1_b     = (const float*)d_in[15];
  const float* ln1_g    = (const float*)d_in[16];
  const float* ln1_b    = (const float*)d_in[17];
  const float* g2_w     = (const float*)d_in[18];
  const float* g2_b     = (const float*)d_in[19];
  const float* gate_temp= (const float*)d_in[20];
  const float* se_p1_w  = (const float*)d_in[21];
  const float* se_p1_b  = (const float*)d_in[22];
  const float* se_p2_w  = (const float*)d_in[23];
  const float* se_p2_b  = (const float*)d_in[24];
  const float* se_ln_g  = (const float*)d_in[25];
  const float* se_ln_b  = (const float*)d_in[26];
  const float* w_ih     = (const float*)d_in[27];
  const float* w_hh     = (const float*)d_in[28];
  const float* b_ih     = (const float*)d_in[29];
  const float* b_hh     = (const float*)d_in[30];

  float* ws = (float*)d_ws;
  size_t off = 0;
  // R region (reused for H1_bf + H2 after proj GEMM consumes R)
  float* Rreg   = ws + off; off += (size_t)82048 * 256 / 2;          // 10,502,144
  // proj region (reused for gq_perm after nbr_post consumes proj)
  float* Preg   = ws + off; off += (size_t)82048 * 128;              // 10,502,144
  float* qv     = ws + off; off += (size_t)BQ * DM;
  float* qe     = ws + off; off += (size_t)BQ * DM;
  float* hout   = ws + off; off += (size_t)BQ * DM;
  float* cstate = ws + off; off += (size_t)BQ * LH;
  float* qv_bfF = ws + off; off += (size_t)BQ * DM / 2;
  float* qe_bfF = ws + off; off += (size_t)BQ * DM / 2;
  float* hbf0F  = ws + off; off += (size_t)BQ * DM / 2;
  float* hbf1F  = ws + off; off += (size_t)BQ * DM / 2;
  float* p1bF   = ws + off; off += 131072 / 2;
  float* p2bF   = ws + off; off += 131072 / 2;
  float* gcnbF  = ws + off; off += 32768 / 2;
  float* wihbF  = ws + off; off += 524288 / 2;
  float* whhbF  = ws + off; off += 524288 / 2;
  float* bihh   = ws + off; off += 2048;
  float* sv     = ws + off; off += 1280;
  float* senc   = ws + off; off += 1280;
  float* sg     = ws + off; off += 256;
  float* s_corr = ws + off; off += 2048;
  float* metaF  = ws + off; off += 8448;

  u16* Rbf    = (u16*)Rreg;
  u16* H1_bf  = (u16*)Rreg;                       // alias: R dead after proj GEMM
  float* H2   = Rreg + (size_t)1048576;           // alias within R region
  float* proj = Preg;
  float* gq   = Preg;                             // alias: proj dead after nbr_post
  u16* qv_bf  = (u16*)qv_bfF;
  u16* qe_bf  = (u16*)qe_bfF;
  u16* hbf0   = (u16*)hbf0F;
  u16* hbf1   = (u16*)hbf1F;
  u16* p1b    = (u16*)p1bF;
  u16* p2b    = (u16*)p2bF;
  u16* gcnb   = (u16*)gcnbF;
  u16* wihb   = (u16*)wihbF;
  u16* whhb   = (u16*)whhbF;
  int* meta   = (int*)metaF;

  // 0. weight casts / permutes
  prep_cast<<<5256, 256, 0, stream>>>(se_p1_w, se_p2_w, gcn_w_w, w_ih, w_hh, b_ih, b_hh,
                                      p1b, p2b, gcnb, wihb, whhb, bihh);

  // 1. gather + top-k -> packed R (bf16)
  nbr_topk_kernel<<<2 * BQ + 2 * F_SUP, 256, 0, stream>>>(
      query, support, q_l1, q_r1, s_l1, s_r1, symbol_emb, Rbf, meta);

  // 2. proj = R @ gcn_w^T   (M=82048, N=128, K=256)
  mfma_gemm<<<641, 256, 0, stream>>>(Rbf, 256, gcnb, 256, 128, 256,
      proj, nullptr, nullptr, nullptr, 0, 0, nullptr, nullptr, nullptr, nullptr);

  // 3. leaky/sum + gate MLP + tanh -> qv (fp32+bf16), sv
  nbr_post_kernel<<<2 * BQ + 2 * F_SUP, 128, 0, stream>>>(
      query, support, q_deg_l, q_deg_r, s_deg_l, s_deg_r, symbol_emb,
      proj, meta, gcn_w_b, gcn_b, g1_w, g1_b, ln1_g, ln1_b, g2_w, g2_b, gate_temp,
      qv, qv_bf, sv);

  // 4. support path (fp32 exact)
  support_enc_kernel<<<F_SUP, 256, 0, stream>>>(sv, se_p1_w, se_p1_b, se_p2_w, se_p2_b,
                                                se_ln_g, se_ln_b, senc);
  support_g_kernel<<<1, 256, 0, stream>>>(senc, w_hh, sg, s_corr);

  // 5. query encoder: H1 = relu(qv@p1^T+b1) [bf16]; H2 = H1@p2^T+b2; qe = LN(H2+qv)
  mfma_gemm<<<(BQ / 128) * (DI / 128), 256, 0, stream>>>(qv_bf, 256, p1b, 256, DI, 256,
      nullptr, H1_bf, se_p1_b, nullptr, 1, 0, nullptr, nullptr, nullptr, nullptr);
  mfma_gemm<<<(BQ / 128) * (DM / 128), 256, 0, stream>>>(H1_bf, 512, p2b, 512, DM, 512,
      H2, nullptr, se_p2_b, nullptr, 0, 0, nullptr, nullptr, nullptr, nullptr);
  ln_residual_kernel<<<BQ, 256, 0, stream>>>(H2, qv, se_ln_g, se_ln_b, qe, qe_bf);

  // 6. gq_perm = qe@w_ih_perm^T + (b_ih+b_hh)_perm
  mfma_gemm<<<(BQ / 128) * (NG / 128), 256, 0, stream>>>(qe_bf, 256, wihb, 256, NG, 256,
      gq, nullptr, bihh, nullptr, 0, 0, nullptr, nullptr, nullptr, nullptr);

  // 7. LSTM step 1 (no GEMM needed)
  lstm_first_kernel<<<(BQ * LH) / 256, 256, 0, stream>>>(gq, qe, cstate, hbf0);

  // 8. steps 2..4: fused GEMM + LSTM epilogue (h_bf ping-pong)
  mfma_gemm<<<(BQ / 128) * (NG / 128), 256, 0, stream>>>(hbf0, 256, whhb, 256, NG, 256,
      nullptr, nullptr, s_corr, gq, 0, 1, cstate, qe, nullptr, hbf1);
  mfma_gemm<<<(BQ / 128) * (NG / 128), 256, 0, stream>>>(hbf1, 256, whhb, 256, NG, 256,
      nullptr, nullptr, s_corr, gq, 0, 1, cstate, qe, nullptr, hbf0);
  mfma_gemm<<<(BQ / 128) * (NG / 128), 256, 0, stream>>>(hbf0, 256, whhb, 256, NG, 256,
      nullptr, nullptr, s_corr, gq, 0, 1, cstate, qe, hout, hbf1);

  // 9. out[m] = dot(h[m], support_g)
  final_dot_kernel<<<BQ, 256, 0, stream>>>(hout, sg, (float*)d_out);
}

// Round 3
// 609.682 us; speedup vs baseline: 1.7873x; 1.2715x over previous
//
#include <hip/hip_runtime.h>
#include <math.h>

#define BQ 4096
#define F_SUP 5
#define MAXK 64
#define ED 128
#define DM 256
#define DI 512
#define LH 512
#define NG 2048
#define PADX 200000
#define KNB 10
#define MROWS 82048           // 8202*10 padded to 641*128
#define MREAL 82020
#define MQ 4224               // 4101 rows padded to 33*128

typedef unsigned short u16;
typedef __attribute__((ext_vector_type(8))) short short8;
typedef __attribute__((ext_vector_type(4))) float floatx4;

__device__ __forceinline__ float sigf(float x) { return 1.0f / (1.0f + __expf(-x)); }
__device__ __forceinline__ float tanh_fast(float x) {
  float a = fabsf(x);
  float e = __expf(-2.0f * a);
  float t = (1.0f - e) / (1.0f + e);
  return copysignf(t, x);
}
__device__ __forceinline__ u16 f2bf(float f) {
  unsigned u = __float_as_uint(f);
  unsigned r = (u + 0x7FFFu + ((u >> 16) & 1u)) >> 16;
  return (u16)r;
}
__device__ __forceinline__ float bf2f(u16 u) {
  return __uint_as_float(((unsigned)u) << 16);
}
__device__ __forceinline__ void gl2lds16(const void* g, void* l) {
  __builtin_amdgcn_global_load_lds(
      (const __attribute__((address_space(1))) void*)g,
      (__attribute__((address_space(3))) void*)l, 16, 0, 0);
}

// ============ phase A: gather + sims + top-k -> selected symbol ids ============
__global__ __launch_bounds__(256) void nbr_topk_kernel(
    const int* __restrict__ query, const int* __restrict__ support,
    const int* __restrict__ q_l1, const int* __restrict__ q_r1,
    const int* __restrict__ s_l1, const int* __restrict__ s_r1,
    const float* __restrict__ emb,
    int* __restrict__ idxA, int* __restrict__ meta)
{
  __shared__ int relS[64], entS[64];
  __shared__ __align__(16) float sE[128];
  __shared__ float simS[64];
  __shared__ int selS[16];
  __shared__ int cntS;
  __shared__ float nsS;

  int tid = threadIdx.x;
  int b = blockIdx.x;
  const int* conn; int self_id;
  if (b < BQ)              { int i = b;              conn = q_l1 + i*(MAXK*2); self_id = query[2*i];   }
  else if (b < 2*BQ)       { int i = b - BQ;         conn = q_r1 + i*(MAXK*2); self_id = query[2*i+1]; }
  else if (b < 2*BQ+F_SUP) { int i = b - 2*BQ;       conn = s_l1 + i*(MAXK*2); self_id = support[2*i]; }
  else                     { int i = b - 2*BQ-F_SUP; conn = s_r1 + i*(MAXK*2); self_id = support[2*i+1]; }

  if (tid < 128) {
    int v = conn[tid];
    if (tid & 1) entS[tid >> 1] = v; else relS[tid >> 1] = v;
    sE[tid] = emb[(long)self_id * ED + tid];
  }
  __syncthreads();
  if (tid < 64) {
    float v = sE[tid]*sE[tid] + sE[tid+64]*sE[tid+64];
    #pragma unroll
    for (int off = 1; off < 64; off <<= 1) v += __shfl_xor(v, off);
    if (tid == 0) nsS = fmaxf(sqrtf(v), 1e-12f);
  }
  __syncthreads();

  {
    int k = tid >> 2, part = tid & 3;
    const float* er = emb + (long)entS[k] * ED + part * 32;
    const float* sr = &sE[part * 32];
    float dot = 0.f, sq = 0.f;
    #pragma unroll
    for (int j = 0; j < 32; j += 4) {
      float4 e = *(const float4*)(er + j);
      float4 s = *(const float4*)(sr + j);
      dot += e.x*s.x + e.y*s.y + e.z*s.z + e.w*s.w;
      sq  += e.x*e.x + e.y*e.y + e.z*e.z + e.w*e.w;
    }
    dot += __shfl_xor(dot, 1); dot += __shfl_xor(dot, 2);
    sq  += __shfl_xor(sq, 1);  sq  += __shfl_xor(sq, 2);
    if (part == 0) {
      float ne = fmaxf(sqrtf(sq), 1e-12f);
      float sim = dot / (nsS * ne);
      if (relS[k] == PADX) sim -= 1e9f;
      simS[k] = sim;
    }
  }
  __syncthreads();

  if (tid < 64) {
    float mys = simS[tid];
    int rank = 0;
    #pragma unroll
    for (int j = 0; j < 64; ++j) {
      float s = simS[j];
      rank += ((s > mys) || (s == mys && j < tid)) ? 1 : 0;
    }
    bool val = (rank < KNB) && (relS[tid] != PADX);
    unsigned long long vm = __ballot(val ? 1 : 0);
    if (val) {
      int pos = __popcll(vm & ((1ull << tid) - 1ull));
      selS[pos] = tid;
    }
    if (tid == 0) { cntS = __popcll(vm); meta[b] = __popcll(vm); }
  }
  __syncthreads();

  int cnt = cntS;
  long base = (long)b * 10;
  if (tid < 2 * KNB) {
    int kk = tid >> 1, h = tid & 1;
    int id = PADX;                                  // PAD row of emb is all zeros
    if (kk < cnt) { int k = selS[kk]; id = h ? entS[k] : relS[k]; }
    idxA[(base + kk) * 2 + h] = id;
  }
  if (b == 0 && tid >= 128 && tid < 128 + 2 * (MROWS - MREAL)) {
    idxA[(long)MREAL * 2 + (tid - 128)] = PADX;     // pad rows -> zero emb row
  }
}

// ============ proj GEMM with fused gather: proj[M,128] = emb[idx] @ gcn_w^T ============
__global__ __launch_bounds__(256) void proj_gather_gemm(
    const int* __restrict__ idxA, const float* __restrict__ emb,
    const u16* __restrict__ W, float* __restrict__ proj)
{
  __shared__ u16 As[128 * 32];
  __shared__ u16 Bs[128 * 32];
  __shared__ int idxS[256];
  int tid = threadIdx.x;
  int bm = blockIdx.x;
  idxS[tid] = idxA[bm * 256 + tid];
  int lane = tid & 63, wave = tid >> 6;
  int wm = (wave & 1) * 64, wn = (wave >> 1) * 64;
  int col = lane & 15, quad = lane >> 4;
  int r = tid >> 1, part = tid & 1;

  floatx4 acc[4][4];
  #pragma unroll
  for (int i = 0; i < 4; ++i)
    #pragma unroll
    for (int j = 0; j < 4; ++j) { floatx4 z = {0.f,0.f,0.f,0.f}; acc[i][j] = z; }
  __syncthreads();

  for (int k0 = 0; k0 < 256; k0 += 32) {
    int half = k0 >> 7, koff = k0 & 127;
    #pragma unroll
    for (int t = 0; t < 2; ++t) {
      int c = t * 256 + tid;
      int rb = c >> 2, o = c & 3;
      int og = o ^ (rb & 3);
      gl2lds16(W + (long)rb * 256 + k0 + og * 8, &Bs[(size_t)c * 8]);
    }
    {
      int id = idxS[r * 2 + half];
      const float* src = emb + (long)id * ED + koff + part * 16;
      float4 f0 = *(const float4*)(src);
      float4 f1 = *(const float4*)(src + 4);
      float4 f2 = *(const float4*)(src + 8);
      float4 f3 = *(const float4*)(src + 12);
      short8 s0, s1;
      s0[0]=(short)f2bf(f0.x); s0[1]=(short)f2bf(f0.y); s0[2]=(short)f2bf(f0.z); s0[3]=(short)f2bf(f0.w);
      s0[4]=(short)f2bf(f1.x); s0[5]=(short)f2bf(f1.y); s0[6]=(short)f2bf(f1.z); s0[7]=(short)f2bf(f1.w);
      s1[0]=(short)f2bf(f2.x); s1[1]=(short)f2bf(f2.y); s1[2]=(short)f2bf(f2.z); s1[3]=(short)f2bf(f2.w);
      s1[4]=(short)f2bf(f3.x); s1[5]=(short)f2bf(f3.y); s1[6]=(short)f2bf(f3.z); s1[7]=(short)f2bf(f3.w);
      int o0 = 2 * part, o1 = 2 * part + 1;
      *(short8*)&As[(size_t)(r * 4 + (o0 ^ (r & 3))) * 8] = s0;
      *(short8*)&As[(size_t)(r * 4 + (o1 ^ (r & 3))) * 8] = s1;
    }
    __syncthreads();
    short8 af[4], bfr[4];
    #pragma unroll
    for (int i = 0; i < 4; ++i) {
      int ra = wm + i * 16 + col;
      af[i] = *(const short8*)&As[(size_t)(ra * 4 + (quad ^ (ra & 3))) * 8];
      int rb = wn + i * 16 + col;
      bfr[i] = *(const short8*)&Bs[(size_t)(rb * 4 + (quad ^ (rb & 3))) * 8];
    }
    #pragma unroll
    for (int i = 0; i < 4; ++i)
      #pragma unroll
      for (int j = 0; j < 4; ++j)
        acc[i][j] = __builtin_amdgcn_mfma_f32_16x16x32_bf16(af[i], bfr[j], acc[i][j], 0, 0, 0);
    __syncthreads();
  }
  int gm0 = bm * 128 + wm + quad * 4;
  int gn0 = wn + col;
  #pragma unroll
  for (int i = 0; i < 4; ++i)
    #pragma unroll
    for (int j = 0; j < 4; ++j)
      #pragma unroll
      for (int rr = 0; rr < 4; ++rr)
        proj[(long)(gm0 + i * 16 + rr) * 128 + gn0 + j * 16] = acc[i][j][rr];
}

// ============ phase C: leaky/sum + gate MLP + tanh output ============
__global__ __launch_bounds__(128) void nbr_post_kernel(
    const int* __restrict__ query, const int* __restrict__ support,
    const int* __restrict__ q_deg_l, const int* __restrict__ q_deg_r,
    const int* __restrict__ s_deg_l, const int* __restrict__ s_deg_r,
    const float* __restrict__ emb,
    const float* __restrict__ proj, const int* __restrict__ meta,
    const float* __restrict__ gcn_w_b, const float* __restrict__ gcn_b,
    const float* __restrict__ g1_w, const float* __restrict__ g1_b,
    const float* __restrict__ ln1_g, const float* __restrict__ ln1_b,
    const float* __restrict__ g2_w, const float* __restrict__ g2_b,
    const float* __restrict__ gate_temp,
    float* __restrict__ qv, u16* __restrict__ qv_bf)
{
  __shared__ __align__(16) float aggS[128];
  __shared__ float sEs[128];
  __shared__ float gateS;
  int tid = threadIdx.x, b = blockIdx.x;
  int deg, self_id, row, colb;
  if (b < BQ)              { int i = b;              deg = q_deg_l[i]; self_id = query[2*i];     row = i;        colb = 0;  }
  else if (b < 2*BQ)       { int i = b - BQ;         deg = q_deg_r[i]; self_id = query[2*i+1];   row = i;        colb = ED; }
  else if (b < 2*BQ+F_SUP) { int i = b - 2*BQ;       deg = s_deg_l[i]; self_id = support[2*i];   row = BQ + i;   colb = 0;  }
  else                     { int i = b - 2*BQ-F_SUP; deg = s_deg_r[i]; self_id = support[2*i+1]; row = BQ + i;   colb = ED; }
  float* outp = qv + (long)row * DM + colb;
  u16*  outpb = qv_bf + (long)row * DM + colb;

  int cnt = meta[b];
  float denom = fmaxf((float)cnt, 1.0f);
  float bsum = gcn_w_b[tid] + gcn_b[tid];
  float agg = 0.f;
  long pbase = (long)b * 10;
  for (int kk = 0; kk < cnt; ++kk) {
    float z = proj[(pbase + kk) * 128 + tid] + bsum;
    z = (z >= 0.f) ? z : 0.01f * z;
    agg += z;
  }
  agg /= denom;
  aggS[tid] = agg;
  sEs[tid] = emb[(long)self_id * ED + tid];
  __syncthreads();

  if (tid < 64) {
    int e = tid;
    const float4* g1r = (const float4*)(g1_w + e * ED);
    float y = g1_b[e];
    #pragma unroll 8
    for (int j = 0; j < 32; ++j) {
      float4 w = g1r[j];
      float4 a = *(const float4*)&aggS[j * 4];
      y += w.x*a.x + w.y*a.y + w.z*a.z + w.w*a.w;
    }
    float s = y;
    #pragma unroll
    for (int off = 1; off < 64; off <<= 1) s += __shfl_xor(s, off);
    float mean = s * (1.0f / 64.0f);
    float dv = y - mean;
    float s2 = dv * dv;
    #pragma unroll
    for (int off = 1; off < 64; off <<= 1) s2 += __shfl_xor(s2, off);
    float var = s2 * (1.0f / 64.0f);
    float hv = dv / sqrtf(var + 1e-5f) * ln1_g[e] + ln1_b[e];
    hv = fmaxf(hv, 0.f);
    float lp = hv * g2_w[e];
    #pragma unroll
    for (int off = 1; off < 64; off <<= 1) lp += __shfl_xor(lp, off);
    if (e == 0) {
      float logit = lp + g2_b[0];
      float temp = fminf(fmaxf(gate_temp[0], 0.1f), 5.0f);
      float gate = 1.0f / (1.0f + expf(-logit / temp));
      if (deg <= 0) gate = 0.f;
      gateS = gate;
    }
  }
  __syncthreads();
  float o = tanhf(sEs[tid] + gateS * aggS[tid]);
  outp[tid] = o;
  outpb[tid] = f2bf(o);
}

// ============ MFMA bf16 GEMM with optional bf16-add / relu / LSTM epilogue ============
__global__ __launch_bounds__(256) void mfma_gemm(
    const u16* __restrict__ A, int lda,
    const u16* __restrict__ W, int ldw,
    int N, int K,
    float* __restrict__ Cout, u16* __restrict__ Cbf,
    const float* __restrict__ bias0, const u16* __restrict__ addbf,
    int relu, int lstm_mode,               // lstm_mode: 0 none, 1 step, 2 first step
    float* __restrict__ cstate, const float* __restrict__ qe,
    u16* __restrict__ hbf)
{
  __shared__ u16 As[128 * 32];
  __shared__ u16 Bs[128 * 32];
  int tid = threadIdx.x;
  int nb = N >> 7;
  int bn = blockIdx.x % nb, bm = blockIdx.x / nb;
  int lane = tid & 63, wave = tid >> 6;
  int wm = (wave & 1) * 64, wn = (wave >> 1) * 64;
  int col = lane & 15, quad = lane >> 4;

  floatx4 acc[4][4];
  #pragma unroll
  for (int i = 0; i < 4; ++i)
    #pragma unroll
    for (int j = 0; j < 4; ++j) { floatx4 z = {0.f,0.f,0.f,0.f}; acc[i][j] = z; }

  for (int k0 = 0; k0 < K; k0 += 32) {
    #pragma unroll
    for (int t = 0; t < 2; ++t) {
      int c = t * 256 + tid;
      int r = c >> 2, o = c & 3;
      int og = o ^ (r & 3);
      gl2lds16(A + (long)(bm * 128 + r) * lda + k0 + og * 8, &As[(size_t)c * 8]);
      gl2lds16(W + (long)(bn * 128 + r) * ldw + k0 + og * 8, &Bs[(size_t)c * 8]);
    }
    __syncthreads();
    short8 af[4], bfr[4];
    #pragma unroll
    for (int i = 0; i < 4; ++i) {
      int ra = wm + i * 16 + col;
      af[i] = *(const short8*)&As[(size_t)(ra * 4 + (quad ^ (ra & 3))) * 8];
      int rb = wn + i * 16 + col;
      bfr[i] = *(const short8*)&Bs[(size_t)(rb * 4 + (quad ^ (rb & 3))) * 8];
    }
    #pragma unroll
    for (int i = 0; i < 4; ++i)
      #pragma unroll
      for (int j = 0; j < 4; ++j)
        acc[i][j] = __builtin_amdgcn_mfma_f32_16x16x32_bf16(af[i], bfr[j], acc[i][j], 0, 0, 0);
    __syncthreads();
  }

  int gm0 = bm * 128 + wm + quad * 4;
  int gn0 = bn * 128 + wn + col;
  #pragma unroll
  for (int i = 0; i < 4; ++i) {
    #pragma unroll
    for (int j = 0; j < 4; ++j) {
      int n = gn0 + j * 16;
      #pragma unroll
      for (int r = 0; r < 4; ++r) {
        int m = gm0 + i * 16 + r;
        float v = acc[i][j][r];
        if (bias0) v += bias0[n];
        if (addbf) v += bf2f(addbf[(long)m * N + n]);
        if (relu) v = fmaxf(v, 0.f);
        if (Cout) Cout[(long)m * N + n] = v;
        if (Cbf)  Cbf[(long)m * N + n] = f2bf(v);
        if (lstm_mode) {
          int g = n & 3;
          float t = (g == 2) ? tanh_fast(v) : sigf(v);
          float t1 = __shfl_xor(t, 1);
          float t2 = __shfl_xor(t, 2);
          float t3 = __shfl_xor(t, 3);
          if (g == 0) {
            int n4 = n >> 2;
            long ci = (long)m * LH + n4;
            float cp = (lstm_mode == 2) ? 0.f : cstate[ci];
            float cn = t1 * cp + t * t2;
            cstate[ci] = cn;
            if (n4 < DM) {
              float hv = qe[(long)m * DM + n4] + t3 * tanh_fast(cn);
              hbf[(long)m * DM + n4] = f2bf(hv);
            }
          }
        }
      }
    }
  }
}

// ============ weight casts + gate-permuted layouts ============
__global__ void prep_cast(
    const float* __restrict__ p1, const float* __restrict__ p2,
    const float* __restrict__ gcnw, const float* __restrict__ wih,
    const float* __restrict__ whh, const float* __restrict__ bih,
    const float* __restrict__ bhh,
    u16* __restrict__ p1b, u16* __restrict__ p2b, u16* __restrict__ gcnb,
    u16* __restrict__ wihb, u16* __restrict__ whhb, float* __restrict__ bihh)
{
  int gid = blockIdx.x * 256 + threadIdx.x;
  if (gid < 131072) { p1b[gid] = f2bf(p1[gid]); }
  else if (gid < 262144) { int i = gid - 131072; p2b[i] = f2bf(p2[i]); }
  else if (gid < 294912) { int i = gid - 262144; gcnb[i] = f2bf(gcnw[i]); }
  else if (gid < 819200) {
    int i = gid - 294912; int npp = i >> 8, k = i & 255;
    int n = (npp & 3) * LH + (npp >> 2);
    wihb[i] = f2bf(wih[(long)n * DM + k]);
  } else if (gid < 1343488) {
    int i = gid - 819200; int npp = i >> 8, k = i & 255;
    int n = (npp & 3) * LH + (npp >> 2);
    whhb[i] = f2bf(whh[(long)n * LH + k]);
  } else if (gid < 1345536) {
    int i = gid - 1343488;
    int n = ((i & 3) * LH) + (i >> 2);
    bihh[i] = bih[n] + bhh[n];
  }
}

// ============ residual layernorm -> qe (fp32 + bf16), rows 0..4100 ============
__global__ __launch_bounds__(256) void ln_residual_kernel(
    const float* __restrict__ h2buf, const float* __restrict__ xbuf,
    const float* __restrict__ lng, const float* __restrict__ lnb,
    float* __restrict__ out, u16* __restrict__ outb)
{
  __shared__ float red[4];
  int r = blockIdx.x, tid = threadIdx.x;
  float v = h2buf[(long)r * DM + tid] + xbuf[(long)r * DM + tid];
  float s = v;
  #pragma unroll
  for (int off = 1; off < 64; off <<= 1) s += __shfl_xor(s, off);
  if ((tid & 63) == 0) red[tid >> 6] = s;
  __syncthreads();
  float mean = (red[0] + red[1] + red[2] + red[3]) * (1.0f / 256.0f);
  __syncthreads();
  float dv = v - mean;
  float s2 = dv * dv;
  #pragma unroll
  for (int off = 1; off < 64; off <<= 1) s2 += __shfl_xor(s2, off);
  if ((tid & 63) == 0) red[tid >> 6] = s2;
  __syncthreads();
  float var = (red[0] + red[1] + red[2] + red[3]) * (1.0f / 256.0f);
  float o = dv / sqrtf(var + 1e-5f) * lng[tid] + lnb[tid];
  out[(long)r * DM + tid] = o;
  outb[(long)r * DM + tid] = f2bf(o);
}

// ============ sg = mean of qe rows 4096..4100 ============
__global__ __launch_bounds__(256) void sg_kernel(const float* __restrict__ qe, float* __restrict__ sg)
{
  int tid = threadIdx.x;
  float v = 0.f;
  #pragma unroll
  for (int r = 0; r < F_SUP; ++r) v += qe[(long)(BQ + r) * DM + tid];
  sg[tid] = v * (1.0f / (float)F_SUP);
}

// ============ s_corr (permuted): one wave per output row ============
__global__ __launch_bounds__(256) void scorr_kernel(
    const float* __restrict__ sg, const float* __restrict__ whh, float* __restrict__ s_corr_perm)
{
  __shared__ float sgS[DM];
  int tid = threadIdx.x;
  sgS[tid] = sg[tid];
  __syncthreads();
  int wave = tid >> 6, lane = tid & 63;
  int n = blockIdx.x * 4 + wave;   // 0..2047
  float4 w = *(const float4*)(whh + (long)n * LH + DM + lane * 4);
  float4 s = *(const float4*)&sgS[lane * 4];
  float d = w.x*s.x + w.y*s.y + w.z*s.z + w.w*s.w;
  #pragma unroll
  for (int off = 1; off < 64; off <<= 1) d += __shfl_xor(d, off);
  if (lane == 0) s_corr_perm[((n & 511) << 2) | (n >> 9)] = d;
}

// ============ final dot (bf16 h) ============
__global__ __launch_bounds__(256) void final_dot_kernel(
    const u16* __restrict__ h, const float* __restrict__ sg, float* __restrict__ out)
{
  __shared__ float red[4];
  int m = blockIdx.x, tid = threadIdx.x;
  float v = bf2f(h[(long)m * DM + tid]) * sg[tid];
  #pragma unroll
  for (int off = 1; off < 64; off <<= 1) v += __shfl_xor(v, off);
  if ((tid & 63) == 0) red[tid >> 6] = v;
  __syncthreads();
  if (tid == 0) out[m] = red[0] + red[1] + red[2] + red[3];
}

extern "C" void kernel_launch(void* const* d_in, const int* in_sizes, int n_in,
                              void* d_out, int out_size, void* d_ws, size_t ws_size,
                              hipStream_t stream)
{
  const int*   query    = (const int*)  d_in[0];
  const int*   support  = (const int*)  d_in[1];
  const int*   q_l1     = (const int*)  d_in[2];
  const int*   q_deg_l  = (const int*)  d_in[3];
  const int*   q_r1     = (const int*)  d_in[4];
  const int*   q_deg_r  = (const int*)  d_in[5];
  const int*   s_l1     = (const int*)  d_in[6];
  const int*   s_deg_l  = (const int*)  d_in[7];
  const int*   s_r1     = (const int*)  d_in[8];
  const int*   s_deg_r  = (const int*)  d_in[9];
  const float* symbol_emb = (const float*)d_in[10];
  const float* gcn_w_w  = (const float*)d_in[11];
  const float* gcn_w_b  = (const float*)d_in[12];
  const float* gcn_b    = (const float*)d_in[13];
  const float* g1_w     = (const float*)d_in[14];
  const float* g1_b     = (const float*)d_in[15];
  const float* ln1_g    = (const float*)d_in[16];
  const float* ln1_b    = (const float*)d_in[17];
  const float* g2_w     = (const float*)d_in[18];
  const float* g2_b     = (const float*)d_in[19];
  const float* gate_temp= (const float*)d_in[20];
  const float* se_p1_w  = (const float*)d_in[21];
  const float* se_p1_b  = (const float*)d_in[22];
  const float* se_p2_w  = (const float*)d_in[23];
  const float* se_p2_b  = (const float*)d_in[24];
  const float* se_ln_g  = (const float*)d_in[25];
  const float* se_ln_b  = (const float*)d_in[26];
  const float* w_ih     = (const float*)d_in[27];
  const float* w_hh     = (const float*)d_in[28];
  const float* b_ih     = (const float*)d_in[29];
  const float* b_hh     = (const float*)d_in[30];

  float* ws = (float*)d_ws;
  size_t off = 0;
  float* projF   = ws + off; off += (size_t)MROWS * 128;          // 10.5M
  float* idxF    = ws + off; off += (size_t)MROWS * 2;
  float* qv      = ws + off; off += (size_t)MQ * DM;
  float* qe      = ws + off; off += (size_t)MQ * DM;
  float* qv_bfF  = ws + off; off += (size_t)MQ * DM / 2;
  float* qe_bfF  = ws + off; off += (size_t)MQ * DM / 2;
  float* h1bF    = ws + off; off += (size_t)MQ * DI / 2;
  float* H2      = ws + off; off += (size_t)MQ * DM;
  float* gqbF    = ws + off; off += (size_t)BQ * NG / 2;
  float* cstate  = ws + off; off += (size_t)BQ * LH;
  float* hbf0F   = ws + off; off += (size_t)BQ * DM / 2;
  float* hbf1F   = ws + off; off += (size_t)BQ * DM / 2;
  float* p1bF    = ws + off; off += 131072 / 2;
  float* p2bF    = ws + off; off += 131072 / 2;
  float* gcnbF   = ws + off; off += 32768 / 2;
  float* wihbF   = ws + off; off += 524288 / 2;
  float* whhbF   = ws + off; off += 524288 / 2;
  float* bihh    = ws + off; off += 2048;
  float* sg      = ws + off; off += 256;
  float* s_corr  = ws + off; off += 2048;
  float* metaF   = ws + off; off += 8448;

  float* proj = projF;
  int* idxA   = (int*)idxF;
  u16* qv_bf  = (u16*)qv_bfF;
  u16* qe_bf  = (u16*)qe_bfF;
  u16* H1_bf  = (u16*)h1bF;
  u16* gq_bf  = (u16*)gqbF;
  u16* hbf0   = (u16*)hbf0F;
  u16* hbf1   = (u16*)hbf1F;
  u16* p1b    = (u16*)p1bF;
  u16* p2b    = (u16*)p2bF;
  u16* gcnb   = (u16*)gcnbF;
  u16* wihb   = (u16*)wihbF;
  u16* whhb   = (u16*)whhbF;
  int* meta   = (int*)metaF;

  // 0. weight casts / permutes
  prep_cast<<<5256, 256, 0, stream>>>(se_p1_w, se_p2_w, gcn_w_w, w_ih, w_hh, b_ih, b_hh,
                                      p1b, p2b, gcnb, wihb, whhb, bihh);

  // 1. gather + top-k -> selected ids
  nbr_topk_kernel<<<2 * BQ + 2 * F_SUP, 256, 0, stream>>>(
      query, support, q_l1, q_r1, s_l1, s_r1, symbol_emb, idxA, meta);

  // 2. proj = emb[idx] @ gcn_w^T   (M=82048, N=128, K=256), gather fused into staging
  proj_gather_gemm<<<MROWS / 128, 256, 0, stream>>>(idxA, symbol_emb, gcnb, proj);

  // 3. leaky/sum + gate MLP + tanh -> qv rows 0..4100 (query + support)
  nbr_post_kernel<<<2 * BQ + 2 * F_SUP, 128, 0, stream>>>(
      query, support, q_deg_l, q_deg_r, s_deg_l, s_deg_r, symbol_emb,
      proj, meta, gcn_w_b, gcn_b, g1_w, g1_b, ln1_g, ln1_b, g2_w, g2_b, gate_temp,
      qv, qv_bf);

  // 4. encoder (query rows + 5 support rows ride along): H1 = relu(qv@p1^T+b1); H2; qe = LN(H2+qv)
  mfma_gemm<<<(MQ / 128) * (DI / 128), 256, 0, stream>>>(qv_bf, 256, p1b, 256, DI, 256,
      nullptr, H1_bf, se_p1_b, nullptr, 1, 0, nullptr, nullptr, nullptr);
  mfma_gemm<<<(MQ / 128) * (DM / 128), 256, 0, stream>>>(H1_bf, 512, p2b, 512, DM, 512,
      H2, nullptr, se_p2_b, nullptr, 0, 0, nullptr, nullptr, nullptr);
  ln_residual_kernel<<<BQ + F_SUP, 256, 0, stream>>>(H2, qv, se_ln_g, se_ln_b, qe, qe_bf);

  // 5. support_g + s_corr (parallel)
  sg_kernel<<<1, 256, 0, stream>>>(qe, sg);
  scorr_kernel<<<512, 256, 0, stream>>>(sg, w_hh, s_corr);

  // 6. gq = qe@w_ih_perm^T + (b_ih+b_hh); fused LSTM step 1 (c_prev=0); store gq as bf16
  mfma_gemm<<<(BQ / 128) * (NG / 128), 256, 0, stream>>>(qe_bf, 256, wihb, 256, NG, 256,
      nullptr, gq_bf, bihh, nullptr, 0, 2, cstate, qe, hbf0);

  // 7. steps 2..4: fused GEMM + LSTM epilogue (h_bf ping-pong)
  mfma_gemm<<<(BQ / 128) * (NG / 128), 256, 0, stream>>>(hbf0, 256, whhb, 256, NG, 256,
      nullptr, nullptr, s_corr, gq_bf, 0, 1, cstate, qe, hbf1);
  mfma_gemm<<<(BQ / 128) * (NG / 128), 256, 0, stream>>>(hbf1, 256, whhb, 256, NG, 256,
      nullptr, nullptr, s_corr, gq_bf, 0, 1, cstate, qe, hbf0);
  mfma_gemm<<<(BQ / 128) * (NG / 128), 256, 0, stream>>>(hbf0, 256, whhb, 256, NG, 256,
      nullptr, nullptr, s_corr, gq_bf, 0, 1, cstate, qe, hbf1);

  // 8. out[m] = dot(h[m], support_g)
  final_dot_kernel<<<BQ, 256, 0, stream>>>(hbf1, sg, (float*)d_out);
}

// Round 4
// 430.669 us; speedup vs baseline: 2.5302x; 1.4157x over previous
//
#include <hip/hip_runtime.h>
#include <math.h>

#define BQ 4096
#define F_SUP 5
#define MAXK 64
#define ED 128
#define DM 256
#define DI 512
#define LH 512
#define NG 2048
#define PADX 200000
#define KNB 10
#define MROWS 82048           // 8202*10 padded to 641*128
#define MREAL 82020
#define MQ 4224               // 4101 rows padded to 33*128

typedef unsigned short u16;
typedef __attribute__((ext_vector_type(8))) short short8;
typedef __attribute__((ext_vector_type(4))) float floatx4;

__device__ __forceinline__ float sigf(float x) { return 1.0f / (1.0f + __expf(-x)); }
__device__ __forceinline__ float tanh_fast(float x) {
  float a = fabsf(x);
  float e = __expf(-2.0f * a);
  float t = (1.0f - e) / (1.0f + e);
  return copysignf(t, x);
}
__device__ __forceinline__ u16 f2bf(float f) {
  unsigned u = __float_as_uint(f);
  unsigned r = (u + 0x7FFFu + ((u >> 16) & 1u)) >> 16;
  return (u16)r;
}
__device__ __forceinline__ float bf2f(u16 u) {
  return __uint_as_float(((unsigned)u) << 16);
}
__device__ __forceinline__ void gl2lds16(const void* g, void* l) {
  __builtin_amdgcn_global_load_lds(
      (const __attribute__((address_space(1))) void*)g,
      (__attribute__((address_space(3))) void*)l, 16, 0, 0);
}

// ============ phase A: gather + sims + top-k -> selected symbol ids ============
__global__ __launch_bounds__(256) void nbr_topk_kernel(
    const int* __restrict__ query, const int* __restrict__ support,
    const int* __restrict__ q_l1, const int* __restrict__ q_r1,
    const int* __restrict__ s_l1, const int* __restrict__ s_r1,
    const float* __restrict__ emb,
    int* __restrict__ idxA, int* __restrict__ meta)
{
  __shared__ int relS[64], entS[64];
  __shared__ __align__(16) float sE[128];
  __shared__ float simS[64];
  __shared__ int selS[16];
  __shared__ int cntS;
  __shared__ float nsS;

  int tid = threadIdx.x;
  int b = blockIdx.x;
  const int* conn; int self_id;
  if (b < BQ)              { int i = b;              conn = q_l1 + i*(MAXK*2); self_id = query[2*i];   }
  else if (b < 2*BQ)       { int i = b - BQ;         conn = q_r1 + i*(MAXK*2); self_id = query[2*i+1]; }
  else if (b < 2*BQ+F_SUP) { int i = b - 2*BQ;       conn = s_l1 + i*(MAXK*2); self_id = support[2*i]; }
  else                     { int i = b - 2*BQ-F_SUP; conn = s_r1 + i*(MAXK*2); self_id = support[2*i+1]; }

  if (tid < 128) {
    int v = conn[tid];
    if (tid & 1) entS[tid >> 1] = v; else relS[tid >> 1] = v;
    sE[tid] = emb[(long)self_id * ED + tid];
  }
  __syncthreads();
  if (tid < 64) {
    float v = sE[tid]*sE[tid] + sE[tid+64]*sE[tid+64];
    #pragma unroll
    for (int off = 1; off < 64; off <<= 1) v += __shfl_xor(v, off);
    if (tid == 0) nsS = fmaxf(sqrtf(v), 1e-12f);
  }
  __syncthreads();

  {
    int k = tid >> 2, part = tid & 3;
    const float* er = emb + (long)entS[k] * ED + part * 32;
    const float* sr = &sE[part * 32];
    float dot = 0.f, sq = 0.f;
    #pragma unroll
    for (int j = 0; j < 32; j += 4) {
      float4 e = *(const float4*)(er + j);
      float4 s = *(const float4*)(sr + j);
      dot += e.x*s.x + e.y*s.y + e.z*s.z + e.w*s.w;
      sq  += e.x*e.x + e.y*e.y + e.z*e.z + e.w*e.w;
    }
    dot += __shfl_xor(dot, 1); dot += __shfl_xor(dot, 2);
    sq  += __shfl_xor(sq, 1);  sq  += __shfl_xor(sq, 2);
    if (part == 0) {
      float ne = fmaxf(sqrtf(sq), 1e-12f);
      float sim = dot / (nsS * ne);
      if (relS[k] == PADX) sim -= 1e9f;
      simS[k] = sim;
    }
  }
  __syncthreads();

  if (tid < 64) {
    float mys = simS[tid];
    int rank = 0;
    #pragma unroll
    for (int j = 0; j < 64; ++j) {
      float s = simS[j];
      rank += ((s > mys) || (s == mys && j < tid)) ? 1 : 0;
    }
    bool val = (rank < KNB) && (relS[tid] != PADX);
    unsigned long long vm = __ballot(val ? 1 : 0);
    if (val) {
      int pos = __popcll(vm & ((1ull << tid) - 1ull));
      selS[pos] = tid;
    }
    if (tid == 0) { cntS = __popcll(vm); meta[b] = __popcll(vm); }
  }
  __syncthreads();

  int cnt = cntS;
  long base = (long)b * 10;
  if (tid < 2 * KNB) {
    int kk = tid >> 1, h = tid & 1;
    int id = PADX;                                  // PAD row of emb is all zeros
    if (kk < cnt) { int k = selS[kk]; id = h ? entS[k] : relS[k]; }
    idxA[(base + kk) * 2 + h] = id;
  }
  if (b == 0 && tid >= 128 && tid < 128 + 2 * (MROWS - MREAL)) {
    idxA[(long)MREAL * 2 + (tid - 128)] = PADX;     // pad rows -> zero emb row
  }
}

// ============ proj GEMM with fused gather: proj[M,128] = emb[idx] @ gcn_w^T ============
__global__ __launch_bounds__(256) void proj_gather_gemm(
    const int* __restrict__ idxA, const float* __restrict__ emb,
    const u16* __restrict__ W, u16* __restrict__ proj)
{
  __shared__ u16 As[128 * 32];
  __shared__ u16 Bs[128 * 32];
  __shared__ int idxS[256];
  int tid = threadIdx.x;
  int bm = blockIdx.x;
  idxS[tid] = idxA[bm * 256 + tid];
  int lane = tid & 63, wave = tid >> 6;
  int wm = (wave & 1) * 64, wn = (wave >> 1) * 64;
  int col = lane & 15, quad = lane >> 4;
  int r = tid >> 1, part = tid & 1;

  floatx4 acc[4][4];
  #pragma unroll
  for (int i = 0; i < 4; ++i)
    #pragma unroll
    for (int j = 0; j < 4; ++j) { floatx4 z = {0.f,0.f,0.f,0.f}; acc[i][j] = z; }
  __syncthreads();

  for (int k0 = 0; k0 < 256; k0 += 32) {
    int half = k0 >> 7, koff = k0 & 127;
    #pragma unroll
    for (int t = 0; t < 2; ++t) {
      int c = t * 256 + tid;
      int rb = c >> 2, o = c & 3;
      int og = o ^ (rb & 3);
      gl2lds16(W + (long)rb * 256 + k0 + og * 8, &Bs[(size_t)c * 8]);
    }
    {
      int id = idxS[r * 2 + half];
      const float* src = emb + (long)id * ED + koff + part * 16;
      float4 f0 = *(const float4*)(src);
      float4 f1 = *(const float4*)(src + 4);
      float4 f2 = *(const float4*)(src + 8);
      float4 f3 = *(const float4*)(src + 12);
      short8 s0, s1;
      s0[0]=(short)f2bf(f0.x); s0[1]=(short)f2bf(f0.y); s0[2]=(short)f2bf(f0.z); s0[3]=(short)f2bf(f0.w);
      s0[4]=(short)f2bf(f1.x); s0[5]=(short)f2bf(f1.y); s0[6]=(short)f2bf(f1.z); s0[7]=(short)f2bf(f1.w);
      s1[0]=(short)f2bf(f2.x); s1[1]=(short)f2bf(f2.y); s1[2]=(short)f2bf(f2.z); s1[3]=(short)f2bf(f2.w);
      s1[4]=(short)f2bf(f3.x); s1[5]=(short)f2bf(f3.y); s1[6]=(short)f2bf(f3.z); s1[7]=(short)f2bf(f3.w);
      int o0 = 2 * part, o1 = 2 * part + 1;
      *(short8*)&As[(size_t)(r * 4 + (o0 ^ (r & 3))) * 8] = s0;
      *(short8*)&As[(size_t)(r * 4 + (o1 ^ (r & 3))) * 8] = s1;
    }
    __syncthreads();
    short8 af[4], bfr[4];
    #pragma unroll
    for (int i = 0; i < 4; ++i) {
      int ra = wm + i * 16 + col;
      af[i] = *(const short8*)&As[(size_t)(ra * 4 + (quad ^ (ra & 3))) * 8];
      int rb = wn + i * 16 + col;
      bfr[i] = *(const short8*)&Bs[(size_t)(rb * 4 + (quad ^ (rb & 3))) * 8];
    }
    #pragma unroll
    for (int i = 0; i < 4; ++i)
      #pragma unroll
      for (int j = 0; j < 4; ++j)
        acc[i][j] = __builtin_amdgcn_mfma_f32_16x16x32_bf16(af[i], bfr[j], acc[i][j], 0, 0, 0);
    __syncthreads();
  }
  int gm0 = bm * 128 + wm + quad * 4;
  int gn0 = wn + col;
  #pragma unroll
  for (int i = 0; i < 4; ++i)
    #pragma unroll
    for (int j = 0; j < 4; ++j)
      #pragma unroll
      for (int rr = 0; rr < 4; ++rr)
        proj[(long)(gm0 + i * 16 + rr) * 128 + gn0 + j * 16] = f2bf(acc[i][j][rr]);
}

// ============ phase C: leaky/sum + gate MLP + tanh output ============
__global__ __launch_bounds__(128) void nbr_post_kernel(
    const int* __restrict__ query, const int* __restrict__ support,
    const int* __restrict__ q_deg_l, const int* __restrict__ q_deg_r,
    const int* __restrict__ s_deg_l, const int* __restrict__ s_deg_r,
    const float* __restrict__ emb,
    const u16* __restrict__ proj, const int* __restrict__ meta,
    const float* __restrict__ gcn_w_b, const float* __restrict__ gcn_b,
    const float* __restrict__ g1_w, const float* __restrict__ g1_b,
    const float* __restrict__ ln1_g, const float* __restrict__ ln1_b,
    const float* __restrict__ g2_w, const float* __restrict__ g2_b,
    const float* __restrict__ gate_temp,
    float* __restrict__ qv, u16* __restrict__ qv_bf)
{
  __shared__ __align__(16) float aggS[128];
  __shared__ float sEs[128];
  __shared__ float gateS;
  int tid = threadIdx.x, b = blockIdx.x;
  int deg, self_id, row, colb;
  if (b < BQ)              { int i = b;              deg = q_deg_l[i]; self_id = query[2*i];     row = i;        colb = 0;  }
  else if (b < 2*BQ)       { int i = b - BQ;         deg = q_deg_r[i]; self_id = query[2*i+1];   row = i;        colb = ED; }
  else if (b < 2*BQ+F_SUP) { int i = b - 2*BQ;       deg = s_deg_l[i]; self_id = support[2*i];   row = BQ + i;   colb = 0;  }
  else                     { int i = b - 2*BQ-F_SUP; deg = s_deg_r[i]; self_id = support[2*i+1]; row = BQ + i;   colb = ED; }
  float* outp = qv + (long)row * DM + colb;
  u16*  outpb = qv_bf + (long)row * DM + colb;

  int cnt = meta[b];
  float denom = fmaxf((float)cnt, 1.0f);
  float bsum = gcn_w_b[tid] + gcn_b[tid];
  float agg = 0.f;
  long pbase = (long)b * 10;
  for (int kk = 0; kk < cnt; ++kk) {
    float z = bf2f(proj[(pbase + kk) * 128 + tid]) + bsum;
    z = (z >= 0.f) ? z : 0.01f * z;
    agg += z;
  }
  agg /= denom;
  aggS[tid] = agg;
  sEs[tid] = emb[(long)self_id * ED + tid];
  __syncthreads();

  if (tid < 64) {
    int e = tid;
    const float4* g1r = (const float4*)(g1_w + e * ED);
    float y = g1_b[e];
    #pragma unroll 8
    for (int j = 0; j < 32; ++j) {
      float4 w = g1r[j];
      float4 a = *(const float4*)&aggS[j * 4];
      y += w.x*a.x + w.y*a.y + w.z*a.z + w.w*a.w;
    }
    float s = y;
    #pragma unroll
    for (int off = 1; off < 64; off <<= 1) s += __shfl_xor(s, off);
    float mean = s * (1.0f / 64.0f);
    float dv = y - mean;
    float s2 = dv * dv;
    #pragma unroll
    for (int off = 1; off < 64; off <<= 1) s2 += __shfl_xor(s2, off);
    float var = s2 * (1.0f / 64.0f);
    float hv = dv / sqrtf(var + 1e-5f) * ln1_g[e] + ln1_b[e];
    hv = fmaxf(hv, 0.f);
    float lp = hv * g2_w[e];
    #pragma unroll
    for (int off = 1; off < 64; off <<= 1) lp += __shfl_xor(lp, off);
    if (e == 0) {
      float logit = lp + g2_b[0];
      float temp = fminf(fmaxf(gate_temp[0], 0.1f), 5.0f);
      float gate = 1.0f / (1.0f + expf(-logit / temp));
      if (deg <= 0) gate = 0.f;
      gateS = gate;
    }
  }
  __syncthreads();
  float o = tanhf(sEs[tid] + gateS * aggS[tid]);
  outp[tid] = o;
  outpb[tid] = f2bf(o);
}

// ============ MFMA bf16 GEMM. lstm_mode: 0 none (row-major C), 1 LSTM step, 2 first LSTM step.
// LSTM modes use the j=gate permutation: position p=(bn<<7)|(wnx<<6)|(j<<4)|col maps to
// gate=j, unit u=bn*32+wnx*16+col. gq/cstate live in C-fragment order (fb=(blk*4+wave)*64+lane).
__global__ __launch_bounds__(256) void mfma_gemm(
    const u16* __restrict__ A, int lda,
    const u16* __restrict__ W, int ldw,
    int N, int K,
    float* __restrict__ Cout, u16* __restrict__ Cbf,
    const float* __restrict__ bias0,
    const u16* __restrict__ gqin,       // lstm_mode==1: fragment-order gates input
    u16* __restrict__ gqout,            // lstm_mode==2: fragment-order gates output
    int relu, int lstm_mode,
    float* __restrict__ cstate, const float* __restrict__ qe,
    u16* __restrict__ hbf)
{
  __shared__ u16 As[128 * 32];
  __shared__ u16 Bs[128 * 32];
  int tid = threadIdx.x;
  int nb = N >> 7;
  int bn = blockIdx.x % nb, bm = blockIdx.x / nb;
  int lane = tid & 63, wave = tid >> 6;
  int wm = (wave & 1) * 64, wn = (wave >> 1) * 64;
  int col = lane & 15, quad = lane >> 4;

  // ---- epilogue input prefetch (latency hides under the K-loop) ----
  u16 gqa[64]; float cpv[16]; float qev[16]; float scv[4];
  int u = 0; long fb = 0;
  if (lstm_mode) {
    u = bn * 32 + (wave >> 1) * 16 + col;
    fb = ((long)blockIdx.x * 4 + wave) * 64 + lane;
    #pragma unroll
    for (int j = 0; j < 4; ++j)
      scv[j] = bias0[bn * 128 + (wave >> 1) * 64 + j * 16 + col];
    if (lstm_mode == 1) {
      const short8* gp = (const short8*)(gqin + fb * 64);
      #pragma unroll
      for (int t = 0; t < 8; ++t) *(short8*)&gqa[t * 8] = gp[t];
      const float4* cp = (const float4*)(cstate + fb * 16);
      #pragma unroll
      for (int t = 0; t < 4; ++t) *(float4*)&cpv[t * 4] = cp[t];
    }
    if (u < DM) {
      #pragma unroll
      for (int i = 0; i < 4; ++i)
        #pragma unroll
        for (int r = 0; r < 4; ++r) {
          int m = bm * 128 + (wave & 1) * 64 + i * 16 + quad * 4 + r;
          qev[i * 4 + r] = qe[(long)m * DM + u];
        }
    }
  }

  floatx4 acc[4][4];
  #pragma unroll
  for (int i = 0; i < 4; ++i)
    #pragma unroll
    for (int j = 0; j < 4; ++j) { floatx4 z = {0.f,0.f,0.f,0.f}; acc[i][j] = z; }

  for (int k0 = 0; k0 < K; k0 += 32) {
    #pragma unroll
    for (int t = 0; t < 2; ++t) {
      int c = t * 256 + tid;
      int r = c >> 2, o = c & 3;
      int og = o ^ (r & 3);
      gl2lds16(A + (long)(bm * 128 + r) * lda + k0 + og * 8, &As[(size_t)c * 8]);
      gl2lds16(W + (long)(bn * 128 + r) * ldw + k0 + og * 8, &Bs[(size_t)c * 8]);
    }
    __syncthreads();
    short8 af[4], bfr[4];
    #pragma unroll
    for (int i = 0; i < 4; ++i) {
      int ra = wm + i * 16 + col;
      af[i] = *(const short8*)&As[(size_t)(ra * 4 + (quad ^ (ra & 3))) * 8];
      int rb = wn + i * 16 + col;
      bfr[i] = *(const short8*)&Bs[(size_t)(rb * 4 + (quad ^ (rb & 3))) * 8];
    }
    #pragma unroll
    for (int i = 0; i < 4; ++i)
      #pragma unroll
      for (int j = 0; j < 4; ++j)
        acc[i][j] = __builtin_amdgcn_mfma_f32_16x16x32_bf16(af[i], bfr[j], acc[i][j], 0, 0, 0);
    __syncthreads();
  }

  if (lstm_mode) {
    float cnew[16];
    #pragma unroll
    for (int i = 0; i < 4; ++i) {
      #pragma unroll
      for (int r = 0; r < 4; ++r) {
        float gI = acc[i][0][r] + scv[0];
        float gF = acc[i][1][r] + scv[1];
        float gG = acc[i][2][r] + scv[2];
        float gO = acc[i][3][r] + scv[3];
        if (lstm_mode == 1) {
          gI += bf2f(gqa[(i * 4 + 0) * 4 + r]);
          gF += bf2f(gqa[(i * 4 + 1) * 4 + r]);
          gG += bf2f(gqa[(i * 4 + 2) * 4 + r]);
          gO += bf2f(gqa[(i * 4 + 3) * 4 + r]);
        }
        float cp = (lstm_mode == 2) ? 0.f : cpv[i * 4 + r];
        float cn = sigf(gF) * cp + sigf(gI) * tanh_fast(gG);
        cnew[i * 4 + r] = cn;
        if (u < DM) {
          int m = bm * 128 + (wave & 1) * 64 + i * 16 + quad * 4 + r;
          hbf[(long)m * DM + u] = f2bf(qev[i * 4 + r] + sigf(gO) * tanh_fast(cn));
        }
      }
    }
    {
      float4* cp = (float4*)(cstate + fb * 16);
      #pragma unroll
      for (int t = 0; t < 4; ++t) cp[t] = *(float4*)&cnew[t * 4];
    }
    if (lstm_mode == 2) {
      u16 ga[64];
      #pragma unroll
      for (int i = 0; i < 4; ++i)
        #pragma unroll
        for (int j = 0; j < 4; ++j)
          #pragma unroll
          for (int r = 0; r < 4; ++r)
            ga[(i * 4 + j) * 4 + r] = f2bf(acc[i][j][r] + scv[j]);
      short8* gp = (short8*)(gqout + fb * 64);
      #pragma unroll
      for (int t = 0; t < 8; ++t) gp[t] = *(short8*)&ga[t * 8];
    }
  } else {
    int gm0 = bm * 128 + wm + quad * 4;
    int gn0 = bn * 128 + wn + col;
    #pragma unroll
    for (int i = 0; i < 4; ++i) {
      #pragma unroll
      for (int j = 0; j < 4; ++j) {
        int n = gn0 + j * 16;
        #pragma unroll
        for (int r = 0; r < 4; ++r) {
          int m = gm0 + i * 16 + r;
          float v = acc[i][j][r];
          if (bias0) v += bias0[n];
          if (relu) v = fmaxf(v, 0.f);
          if (Cout) Cout[(long)m * N + n] = v;
          if (Cbf)  Cbf[(long)m * N + n] = f2bf(v);
        }
      }
    }
  }
}

// ============ weight casts + j=gate permuted layouts ============
// position p in [0,2048): g=(p>>4)&3, u=(p>>7)*32+((p>>6)&1)*16+(p&15), orig row n=g*512+u
__global__ void prep_cast(
    const float* __restrict__ p1, const float* __restrict__ p2,
    const float* __restrict__ gcnw, const float* __restrict__ wih,
    const float* __restrict__ whh, const float* __restrict__ bih,
    const float* __restrict__ bhh,
    u16* __restrict__ p1b, u16* __restrict__ p2b, u16* __restrict__ gcnb,
    u16* __restrict__ wihb, u16* __restrict__ whhb, float* __restrict__ bihh)
{
  int gid = blockIdx.x * 256 + threadIdx.x;
  if (gid < 131072) { p1b[gid] = f2bf(p1[gid]); }
  else if (gid < 262144) { int i = gid - 131072; p2b[i] = f2bf(p2[i]); }
  else if (gid < 294912) { int i = gid - 262144; gcnb[i] = f2bf(gcnw[i]); }
  else if (gid < 819200) {
    int i = gid - 294912; int p = i >> 8, k = i & 255;
    int g = (p >> 4) & 3, uu = (p >> 7) * 32 + ((p >> 6) & 1) * 16 + (p & 15);
    int n = g * 512 + uu;
    wihb[i] = f2bf(wih[(long)n * DM + k]);
  } else if (gid < 1343488) {
    int i = gid - 819200; int p = i >> 8, k = i & 255;
    int g = (p >> 4) & 3, uu = (p >> 7) * 32 + ((p >> 6) & 1) * 16 + (p & 15);
    int n = g * 512 + uu;
    whhb[i] = f2bf(whh[(long)n * LH + k]);
  } else if (gid < 1345536) {
    int p = gid - 1343488;
    int g = (p >> 4) & 3, uu = (p >> 7) * 32 + ((p >> 6) & 1) * 16 + (p & 15);
    int n = g * 512 + uu;
    bihh[p] = bih[n] + bhh[n];
  }
}

// ============ residual layernorm -> qe (fp32 + bf16), rows 0..4100 ============
__global__ __launch_bounds__(256) void ln_residual_kernel(
    const float* __restrict__ h2buf, const float* __restrict__ xbuf,
    const float* __restrict__ lng, const float* __restrict__ lnb,
    float* __restrict__ out, u16* __restrict__ outb)
{
  __shared__ float red[4];
  int r = blockIdx.x, tid = threadIdx.x;
  float v = h2buf[(long)r * DM + tid] + xbuf[(long)r * DM + tid];
  float s = v;
  #pragma unroll
  for (int off = 1; off < 64; off <<= 1) s += __shfl_xor(s, off);
  if ((tid & 63) == 0) red[tid >> 6] = s;
  __syncthreads();
  float mean = (red[0] + red[1] + red[2] + red[3]) * (1.0f / 256.0f);
  __syncthreads();
  float dv = v - mean;
  float s2 = dv * dv;
  #pragma unroll
  for (int off = 1; off < 64; off <<= 1) s2 += __shfl_xor(s2, off);
  if ((tid & 63) == 0) red[tid >> 6] = s2;
  __syncthreads();
  float var = (red[0] + red[1] + red[2] + red[3]) * (1.0f / 256.0f);
  float o = dv / sqrtf(var + 1e-5f) * lng[tid] + lnb[tid];
  out[(long)r * DM + tid] = o;
  outb[(long)r * DM + tid] = f2bf(o);
}

// ============ sg (mean of qe rows 4096..4100) + permuted s_corr ============
__global__ __launch_bounds__(256) void scorr_kernel(
    const float* __restrict__ qe, const float* __restrict__ whh,
    float* __restrict__ sg, float* __restrict__ s_corr_perm)
{
  __shared__ float sgS[DM];
  int tid = threadIdx.x;
  {
    float v = 0.f;
    #pragma unroll
    for (int r = 0; r < F_SUP; ++r) v += qe[(long)(BQ + r) * DM + tid];
    v *= (1.0f / (float)F_SUP);
    sgS[tid] = v;
    if (blockIdx.x == 0) sg[tid] = v;
  }
  __syncthreads();
  int wave = tid >> 6, lane = tid & 63;
  int n = blockIdx.x * 4 + wave;   // orig row 0..2047
  float4 w = *(const float4*)(whh + (long)n * LH + DM + lane * 4);
  float4 s = *(const float4*)&sgS[lane * 4];
  float d = w.x*s.x + w.y*s.y + w.z*s.z + w.w*s.w;
  #pragma unroll
  for (int off = 1; off < 64; off <<= 1) d += __shfl_xor(d, off);
  if (lane == 0) {
    int g = n >> 9, uu = n & 511;
    int p = (uu >> 5) * 128 + ((uu >> 4) & 1) * 64 + g * 16 + (uu & 15);
    s_corr_perm[p] = d;
  }
}

// ============ final dot (bf16 h) ============
__global__ __launch_bounds__(256) void final_dot_kernel(
    const u16* __restrict__ h, const float* __restrict__ sg, float* __restrict__ out)
{
  __shared__ float red[4];
  int m = blockIdx.x, tid = threadIdx.x;
  float v = bf2f(h[(long)m * DM + tid]) * sg[tid];
  #pragma unroll
  for (int off = 1; off < 64; off <<= 1) v += __shfl_xor(v, off);
  if ((tid & 63) == 0) red[tid >> 6] = v;
  __syncthreads();
  if (tid == 0) out[m] = red[0] + red[1] + red[2] + red[3];
}

extern "C" void kernel_launch(void* const* d_in, const int* in_sizes, int n_in,
                              void* d_out, int out_size, void* d_ws, size_t ws_size,
                              hipStream_t stream)
{
  const int*   query    = (const int*)  d_in[0];
  const int*   support  = (const int*)  d_in[1];
  const int*   q_l1     = (const int*)  d_in[2];
  const int*   q_deg_l  = (const int*)  d_in[3];
  const int*   q_r1     = (const int*)  d_in[4];
  const int*   q_deg_r  = (const int*)  d_in[5];
  const int*   s_l1     = (const int*)  d_in[6];
  const int*   s_deg_l  = (const int*)  d_in[7];
  const int*   s_r1     = (const int*)  d_in[8];
  const int*   s_deg_r  = (const int*)  d_in[9];
  const float* symbol_emb = (const float*)d_in[10];
  const float* gcn_w_w  = (const float*)d_in[11];
  const float* gcn_w_b  = (const float*)d_in[12];
  const float* gcn_b    = (const float*)d_in[13];
  const float* g1_w     = (const float*)d_in[14];
  const float* g1_b     = (const float*)d_in[15];
  const float* ln1_g    = (const float*)d_in[16];
  const float* ln1_b    = (const float*)d_in[17];
  const float* g2_w     = (const float*)d_in[18];
  const float* g2_b     = (const float*)d_in[19];
  const float* gate_temp= (const float*)d_in[20];
  const float* se_p1_w  = (const float*)d_in[21];
  const float* se_p1_b  = (const float*)d_in[22];
  const float* se_p2_w  = (const float*)d_in[23];
  const float* se_p2_b  = (const float*)d_in[24];
  const float* se_ln_g  = (const float*)d_in[25];
  const float* se_ln_b  = (const float*)d_in[26];
  const float* w_ih     = (const float*)d_in[27];
  const float* w_hh     = (const float*)d_in[28];
  const float* b_ih     = (const float*)d_in[29];
  const float* b_hh     = (const float*)d_in[30];

  float* ws = (float*)d_ws;
  size_t off = 0;
  float* projF   = ws + off; off += (size_t)MROWS * 128 / 2;      // bf16 proj
  float* idxF    = ws + off; off += (size_t)MROWS * 2;
  float* qv      = ws + off; off += (size_t)MQ * DM;
  float* qe      = ws + off; off += (size_t)MQ * DM;
  float* qv_bfF  = ws + off; off += (size_t)MQ * DM / 2;
  float* qe_bfF  = ws + off; off += (size_t)MQ * DM / 2;
  float* h1bF    = ws + off; off += (size_t)MQ * DI / 2;
  float* H2      = ws + off; off += (size_t)MQ * DM;
  float* gqbF    = ws + off; off += (size_t)BQ * NG / 2;          // fragment-order gates (bf16)
  float* cstate  = ws + off; off += (size_t)BQ * LH;              // fragment-order c (fp32)
  float* hbf0F   = ws + off; off += (size_t)BQ * DM / 2;
  float* hbf1F   = ws + off; off += (size_t)BQ * DM / 2;
  float* p1bF    = ws + off; off += 131072 / 2;
  float* p2bF    = ws + off; off += 131072 / 2;
  float* gcnbF   = ws + off; off += 32768 / 2;
  float* wihbF   = ws + off; off += 524288 / 2;
  float* whhbF   = ws + off; off += 524288 / 2;
  float* bihh    = ws + off; off += 2048;
  float* sg      = ws + off; off += 256;
  float* s_corr  = ws + off; off += 2048;
  float* metaF   = ws + off; off += 8448;

  u16* proj   = (u16*)projF;
  int* idxA   = (int*)idxF;
  u16* qv_bf  = (u16*)qv_bfF;
  u16* qe_bf  = (u16*)qe_bfF;
  u16* H1_bf  = (u16*)h1bF;
  u16* gq_fr  = (u16*)gqbF;
  u16* hbf0   = (u16*)hbf0F;
  u16* hbf1   = (u16*)hbf1F;
  u16* p1b    = (u16*)p1bF;
  u16* p2b    = (u16*)p2bF;
  u16* gcnb   = (u16*)gcnbF;
  u16* wihb   = (u16*)wihbF;
  u16* whhb   = (u16*)whhbF;
  int* meta   = (int*)metaF;

  // 0. weight casts / permutes
  prep_cast<<<5256, 256, 0, stream>>>(se_p1_w, se_p2_w, gcn_w_w, w_ih, w_hh, b_ih, b_hh,
                                      p1b, p2b, gcnb, wihb, whhb, bihh);

  // 1. gather + top-k -> selected ids
  nbr_topk_kernel<<<2 * BQ + 2 * F_SUP, 256, 0, stream>>>(
      query, support, q_l1, q_r1, s_l1, s_r1, symbol_emb, idxA, meta);

  // 2. proj = emb[idx] @ gcn_w^T   (M=82048, N=128, K=256), gather fused into staging
  proj_gather_gemm<<<MROWS / 128, 256, 0, stream>>>(idxA, symbol_emb, gcnb, proj);

  // 3. leaky/sum + gate MLP + tanh -> qv rows 0..4100 (query + support)
  nbr_post_kernel<<<2 * BQ + 2 * F_SUP, 128, 0, stream>>>(
      query, support, q_deg_l, q_deg_r, s_deg_l, s_deg_r, symbol_emb,
      proj, meta, gcn_w_b, gcn_b, g1_w, g1_b, ln1_g, ln1_b, g2_w, g2_b, gate_temp,
      qv, qv_bf);

  // 4. encoder (query + 5 support rows ride along)
  mfma_gemm<<<(MQ / 128) * (DI / 128), 256, 0, stream>>>(qv_bf, 256, p1b, 256, DI, 256,
      nullptr, H1_bf, se_p1_b, nullptr, nullptr, 1, 0, nullptr, nullptr, nullptr);
  mfma_gemm<<<(MQ / 128) * (DM / 128), 256, 0, stream>>>(H1_bf, 512, p2b, 512, DM, 512,
      H2, nullptr, se_p2_b, nullptr, nullptr, 0, 0, nullptr, nullptr, nullptr);
  ln_residual_kernel<<<BQ + F_SUP, 256, 0, stream>>>(H2, qv, se_ln_g, se_ln_b, qe, qe_bf);

  // 5. support_g + permuted s_corr
  scorr_kernel<<<512, 256, 0, stream>>>(qe, w_hh, sg, s_corr);

  // 6. gq = qe@w_ih_perm^T + (b_ih+b_hh); fused LSTM step 1; gates stored fragment-order
  mfma_gemm<<<(BQ / 128) * (NG / 128), 256, 0, stream>>>(qe_bf, 256, wihb, 256, NG, 256,
      nullptr, nullptr, bihh, nullptr, gq_fr, 0, 2, cstate, qe, hbf0);

  // 7. steps 2..4: fused GEMM + in-thread LSTM epilogue (h ping-pong)
  mfma_gemm<<<(BQ / 128) * (NG / 128), 256, 0, stream>>>(hbf0, 256, whhb, 256, NG, 256,
      nullptr, nullptr, s_corr, gq_fr, nullptr, 0, 1, cstate, qe, hbf1);
  mfma_gemm<<<(BQ / 128) * (NG / 128), 256, 0, stream>>>(hbf1, 256, whhb, 256, NG, 256,
      nullptr, nullptr, s_corr, gq_fr, nullptr, 0, 1, cstate, qe, hbf0);
  mfma_gemm<<<(BQ / 128) * (NG / 128), 256, 0, stream>>>(hbf0, 256, whhb, 256, NG, 256,
      nullptr, nullptr, s_corr, gq_fr, nullptr, 0, 1, cstate, qe, hbf1);

  // 8. out[m] = dot(h[m], support_g)
  final_dot_kernel<<<BQ, 256, 0, stream>>>(hbf1, sg, (float*)d_out);
}